// Round 3
// baseline (365.618 us; speedup 1.0000x reference)
//
#include <hip/hip_runtime.h>
#include <hip/hip_bf16.h>
#include <math.h>

// Problem constants
#define BB 8
#define CIN 256
#define FI 64
#define HW 4096
#define C8 8
#define EPS 1e-5f
#define LOG2E 1.4426950408889634f

typedef __attribute__((ext_vector_type(8))) short bf16x8;
typedef __attribute__((ext_vector_type(4))) float f32x4;
typedef unsigned short u16;

static __device__ __forceinline__ u16 f2b(float x) {
    unsigned u = __builtin_bit_cast(unsigned, x);
    return (u16)((u + 0x8000u) >> 16);
}
static __device__ __forceinline__ unsigned pk2(float a, float b) {
    unsigned ua = __builtin_bit_cast(unsigned, a);
    unsigned ub = __builtin_bit_cast(unsigned, b);
    return ((ua + 0x8000u) >> 16) | ((ub + 0x8000u) & 0xffff0000u);
}
// single-instruction packed f32->bf16 (RNE)
static __device__ __forceinline__ unsigned cvtpk(float a, float b) {
    unsigned r;
    asm("v_cvt_pk_bf16_f32 %0, %1, %2" : "=v"(r) : "v"(a), "v"(b));
    return r;
}
static __device__ __forceinline__ float b2f(u16 v) {
    return __builtin_bit_cast(float, ((unsigned)v) << 16);
}

// ---------------------------------------------------------------------------
// K0: fold BN into psi-conv weights (Wp bf16 [64][512], Cp fp32[64]) and
// build concatenated PAM weights (Wcat bf16 [80][64], bcat fp32[80]).
// pb rows (fb = PAM query) are pre-scaled by log2(e) so the PAM softmax can
// run in exp2 domain with bare v_exp_f32.
// ---------------------------------------------------------------------------
__global__ __launch_bounds__(256) void k_prep(
    const float* __restrict__ Wg, const float* __restrict__ Wgb,
    const float* __restrict__ gg, const float* __restrict__ gbeta,
    const float* __restrict__ gm, const float* __restrict__ gv,
    const float* __restrict__ Wx, const float* __restrict__ Wxb,
    const float* __restrict__ xg, const float* __restrict__ xbeta,
    const float* __restrict__ xm, const float* __restrict__ xv,
    const float* __restrict__ pbw, const float* __restrict__ pbb,
    const float* __restrict__ pcw, const float* __restrict__ pcb,
    const float* __restrict__ pdw, const float* __restrict__ pdb,
    u16* __restrict__ Wp, float* __restrict__ Cp,
    u16* __restrict__ Wcat, float* __restrict__ bcat)
{
    const int gid = blockIdx.x * 256 + threadIdx.x;
    for (int idx = gid; idx < FI * 512; idx += 4096) {
        int o = idx >> 9, k = idx & 511;
        float s, w;
        if (k < 256) { s = gg[o] * rsqrtf(gv[o] + EPS); w = Wg[o * 256 + k]; }
        else         { s = xg[o] * rsqrtf(xv[o] + EPS); w = Wx[o * 256 + k - 256]; }
        Wp[idx] = f2b(w * s);
    }
    for (int idx = gid; idx < 80 * 64; idx += 4096) {
        int row = idx >> 6, col = idx & 63;
        float w;
        if (row < 8)       w = pbw[row * 64 + col] * LOG2E;   // exp2-domain queries
        else if (row < 16) w = pcw[(row - 8) * 64 + col];
        else               w = pdw[(row - 16) * 64 + col];
        Wcat[idx] = f2b(w);
    }
    if (blockIdx.x == 0) {
        int tid = threadIdx.x;
        if (tid < FI) {
            float ig = gg[tid] * rsqrtf(gv[tid] + EPS);
            float ix = xg[tid] * rsqrtf(xv[tid] + EPS);
            Cp[tid] = (Wgb[tid] - gm[tid]) * ig + gbeta[tid]
                    + (Wxb[tid] - xm[tid]) * ix + xbeta[tid];
        }
        if (tid >= 64 && tid < 144) {
            int r = tid - 64;
            float bv = (r < 8) ? pbb[r] * LOG2E : (r < 16 ? pcb[r - 8] : pdb[r - 16]);
            bcat[r] = bv;
        }
    }
}

// ---------------------------------------------------------------------------
// K1: psi = relu(W' @ cat(g,x) + C) via bf16 MFMA, FUSED with fbcd:
// emits psiB/psiLo bf16 [B][64][4096], fbcT bf16 [B][4096][16],
// fdB bf16 [B][64][4096]. psi^T lives only in LDS.
// grid (64 px-tiles, 8 b) x 256
// ---------------------------------------------------------------------------
__global__ __launch_bounds__(256) void k_psi(
    const float* __restrict__ g, const float* __restrict__ x,
    const u16* __restrict__ Wp, const float* __restrict__ Cp,
    const u16* __restrict__ Wcat, const float* __restrict__ bcat,
    u16* __restrict__ psiB, u16* __restrict__ psiLo,
    u16* __restrict__ fbcT, u16* __restrict__ fdB)
{
    const int tid  = threadIdx.x;
    const int lane = tid & 63;
    const int w    = tid >> 6;
    const int n    = lane & 15;
    const int quad = lane >> 4;
    const int b    = blockIdx.y;
    const int p0   = blockIdx.x * 64;

    __shared__ u16 InT[64][72];   // in: [px][ch]; later psi^T, later Tfd [ch][px]
    __shared__ u16 Tbc[64][16];   // [px][out16]

    f32x4 acc[4];
#pragma unroll
    for (int mt = 0; mt < 4; ++mt) acc[mt] = (f32x4){0.f, 0.f, 0.f, 0.f};

    for (int kc = 0; kc < 8; ++kc) {
        const float* src = (kc < 4) ? g : x;
        const int ch0 = (kc & 3) * 64;
        __syncthreads();
#pragma unroll
        for (int r = 0; r < 4; ++r) {
            int ch = (tid >> 4) + r * 16;
            int px = (tid & 15) * 4;
            float4 v = *(const float4*)&src[((size_t)b * CIN + ch0 + ch) * HW + p0 + px];
            InT[px][ch]     = f2b(v.x);
            InT[px + 1][ch] = f2b(v.y);
            InT[px + 2][ch] = f2b(v.z);
            InT[px + 3][ch] = f2b(v.w);
        }
        __syncthreads();
#pragma unroll
        for (int ks = 0; ks < 2; ++ks) {
            const int kglob = kc * 64 + ks * 32;
            bf16x8 bfrag = *(const bf16x8*)&InT[w * 16 + n][ks * 32 + quad * 8];
#pragma unroll
            for (int mt = 0; mt < 4; ++mt) {
                bf16x8 af = *(const bf16x8*)&Wp[(mt * 16 + n) * 512 + kglob + quad * 8];
                acc[mt] = __builtin_amdgcn_mfma_f32_16x16x32_bf16(
                              af, bfrag, acc[mt], 0, 0, 0);
            }
        }
    }

    // bias + relu; store psiB(hi)+psiLo; build psi^T in InT
    float pv[4][4];
#pragma unroll
    for (int mt = 0; mt < 4; ++mt)
#pragma unroll
        for (int r = 0; r < 4; ++r) {
            int c = mt * 16 + quad * 4 + r;
            float v = acc[mt][r] + Cp[c];
            v = v > 0.f ? v : 0.f;
            pv[mt][r] = v;
            u16 hb = f2b(v);
            size_t idx = ((size_t)b * FI + c) * HW + p0 + w * 16 + n;
            psiB[idx]  = hb;
            psiLo[idx] = f2b(v - b2f(hb));
        }
    __syncthreads();   // staging reads done
#pragma unroll
    for (int mt = 0; mt < 4; ++mt) {
        *(unsigned*)&InT[w * 16 + n][mt * 16 + quad * 4]     = cvtpk(pv[mt][0], pv[mt][1]);
        *(unsigned*)&InT[w * 16 + n][mt * 16 + quad * 4 + 2] = cvtpk(pv[mt][2], pv[mt][3]);
    }
    __syncthreads();

    // fbcd MFMAs: A = psi^T rows (px), B = Wcat (L2-resident)
    f32x4 facc[5];
#pragma unroll
    for (int nt = 0; nt < 5; ++nt) facc[nt] = (f32x4){0.f, 0.f, 0.f, 0.f};
#pragma unroll
    for (int ks = 0; ks < 2; ++ks) {
        bf16x8 af = *(const bf16x8*)&InT[w * 16 + n][ks * 32 + quad * 8];
#pragma unroll
        for (int nt = 0; nt < 5; ++nt) {
            bf16x8 bf = *(const bf16x8*)&Wcat[(nt * 16 + n) * FI + ks * 32 + quad * 8];
            facc[nt] = __builtin_amdgcn_mfma_f32_16x16x32_bf16(af, bf, facc[nt], 0, 0, 0);
        }
    }
    __syncthreads();   // all psi^T reads done; reuse InT as Tfd [ch][px]

    {
        float bias = bcat[n];
#pragma unroll
        for (int r = 0; r < 4; ++r)
            Tbc[w * 16 + quad * 4 + r][n] = f2b(facc[0][r] + bias);
    }
#pragma unroll
    for (int nt = 1; nt < 5; ++nt) {
        int ch = (nt - 1) * 16 + n;
        float bias = bcat[nt * 16 + n];
        *(unsigned*)&InT[ch][w * 16 + quad * 4]     = cvtpk(facc[nt][0] + bias, facc[nt][1] + bias);
        *(unsigned*)&InT[ch][w * 16 + quad * 4 + 2] = cvtpk(facc[nt][2] + bias, facc[nt][3] + bias);
    }
    __syncthreads();
    {   // fbcT: 64 rows x 16 el
        int row = tid >> 2, part = tid & 3;
        uint2 v = *(const uint2*)&Tbc[row][part * 4];
        *(uint2*)&fbcT[((size_t)b * HW + p0 + row) * 16 + part * 4] = v;
    }
#pragma unroll
    for (int rep = 0; rep < 2; ++rep) {   // fdB: 64 ch x 64 px
        int t = rep * 256 + tid;
        int ch = t >> 3, seg = t & 7;
        bf16x8 v = *(const bf16x8*)&InT[ch][seg * 8];
        *(bf16x8*)&fdB[((size_t)b * FI + ch) * HW + p0 + seg * 8] = v;
    }
}

// ---------------------------------------------------------------------------
// K3a: Gram partials via compensated bf16 MFMA (hi*hi + hi*lo + lo*hi).
// grid (32 slices, 8 b) x 256 -> Gp[s][b][64][64]
// ---------------------------------------------------------------------------
__global__ __launch_bounds__(256) void k_gram(
    const u16* __restrict__ psiB, const u16* __restrict__ psiLo,
    float* __restrict__ Gp)
{
    const int tid  = threadIdx.x;
    const int lane = tid & 63;
    const int w    = tid >> 6;
    const int n    = lane & 15;
    const int quad = lane >> 4;
    const int s    = blockIdx.x;
    const int b    = blockIdx.y;

    f32x4 acc[4];
#pragma unroll
    for (int nt = 0; nt < 4; ++nt) acc[nt] = (f32x4){0.f, 0.f, 0.f, 0.f};

    for (int ks = 0; ks < 4; ++ks) {
        const int k0 = s * 128 + ks * 32;
        const size_t ra = ((size_t)b * FI + w * 16 + n) * HW + k0 + quad * 8;
        bf16x8 ah = *(const bf16x8*)&psiB[ra];
        bf16x8 al = *(const bf16x8*)&psiLo[ra];
#pragma unroll
        for (int nt = 0; nt < 4; ++nt) {
            const size_t rb = ((size_t)b * FI + nt * 16 + n) * HW + k0 + quad * 8;
            bf16x8 bh = *(const bf16x8*)&psiB[rb];
            bf16x8 bl = *(const bf16x8*)&psiLo[rb];
            acc[nt] = __builtin_amdgcn_mfma_f32_16x16x32_bf16(ah, bh, acc[nt], 0, 0, 0);
            acc[nt] = __builtin_amdgcn_mfma_f32_16x16x32_bf16(ah, bl, acc[nt], 0, 0, 0);
            acc[nt] = __builtin_amdgcn_mfma_f32_16x16x32_bf16(al, bh, acc[nt], 0, 0, 0);
        }
    }
#pragma unroll
    for (int nt = 0; nt < 4; ++nt)
#pragma unroll
        for (int r = 0; r < 4; ++r) {
            int i = w * 16 + quad * 4 + r;
            Gp[(((size_t)s * 8 + b) * 64 + i) * 64 + nt * 16 + n] = acc[nt][r];
        }
}

// ---------------------------------------------------------------------------
// K3b: CAM softmax of (rowmax - G).  grid (8 b, 4 grp) x 256
// ---------------------------------------------------------------------------
__global__ __launch_bounds__(256) void k_camsm(
    const float* __restrict__ Gp, float* __restrict__ att)
{
    const int tid = threadIdx.x, d = tid & 63, ty = tid >> 6;
    const int b = blockIdx.x, grp = blockIdx.y;
#pragma unroll 1
    for (int rr = 0; rr < 4; ++rr) {
        int i = grp * 16 + ty * 4 + rr;
        float gsum = 0.f;
#pragma unroll 1
        for (int s = 0; s < 32; ++s) gsum += Gp[(((size_t)s * 8 + b) * 64 + i) * 64 + d];
        float M = gsum;
#pragma unroll
        for (int msk = 1; msk < 64; msk <<= 1) M = fmaxf(M, __shfl_xor(M, msk));
        float a = M - gsum;
        float m2 = a;
#pragma unroll
        for (int msk = 1; msk < 64; msk <<= 1) m2 = fmaxf(m2, __shfl_xor(m2, msk));
        float p = __expf(a - m2);
        float ssum = p;
#pragma unroll
        for (int msk = 1; msk < 64; msk <<= 1) ssum += __shfl_xor(ssum, msk);
        att[((size_t)b * 64 + i) * 64 + d] = p / ssum;
    }
}

// ---------------------------------------------------------------------------
// K5: PAM flash attention — BARRIER-FREE. K/V fragments load directly from
// L1/L2 (fbcT/fdB); only the per-wave P transpose goes through LDS.
// K is register-ping-pong prefetched one chunk ahead. exp2-domain softmax,
// defer-rescale (THR=8), cvt_pk packing, setprio around MFMA clusters.
// grid (8 b, 64 qtile, 2 part) x 256. Emits normalized bf16 partials
// Opart[p][b][c][pix] + ml[p][b][pix] = (m, l)   (m in log2 units).
// ---------------------------------------------------------------------------
__global__ __launch_bounds__(256) void k_pam(
    const u16* __restrict__ fbcT, const u16* __restrict__ fdB,
    u16* __restrict__ Opart, float* __restrict__ ml)
{
    const int tid  = threadIdx.x;
    const int lane = tid & 63;
    const int w    = tid >> 6;
    const int n    = lane & 15;
    const int quad = lane >> 4;
    const int b    = blockIdx.x;
    const int i0   = blockIdx.y * 64;
    const int p    = blockIdx.z;
    const int jstart = p * 32, jend = jstart + 32;

    __shared__ u16 Ps[4][16][72];  // per-wave P^T [q_local][key]

    // Q fragment in regs: quad 0 = real fb (8 dims), quads 1-3 = zero cols.
    bf16x8 qfrag = {};
    if (quad == 0)
        qfrag = *(const bf16x8*)&fbcT[((size_t)b * HW + i0 + w * 16 + n) * 16];

    // K rows: fc part = cols 8..15 of fbcT row (j0 + mt*16 + n). All quads
    // load row n (quads 1-3 carry dead data killed by zero Q cols).
    const u16* kbase = fbcT + (size_t)b * HW * 16 + 8;
    // V fragments: fdB[b*FI + mt*16+n][j0 + k0*32 + quad*8]
    const u16* vbase = fdB + ((size_t)b * FI + n) * HW + quad * 8;

    f32x4 oacc[4];
#pragma unroll
    for (int mt = 0; mt < 4; ++mt) oacc[mt] = (f32x4){0.f, 0.f, 0.f, 0.f};
    float m = -1e30f, l = 0.f;   // l = per-lane partial (this quad's keys)

    // preload K for first chunk
    bf16x8 kc0, kc1, kc2, kc3;
    {
        const u16* kp = kbase + (size_t)(jstart * 64 + n) * 16;
        kc0 = *(const bf16x8*)(kp);
        kc1 = *(const bf16x8*)(kp + 256);
        kc2 = *(const bf16x8*)(kp + 512);
        kc3 = *(const bf16x8*)(kp + 768);
    }
    bf16x8 kn0, kn1, kn2, kn3;

#define PAM_BODY(KA0, KA1, KA2, KA3, KB0, KB1, KB2, KB3, JC)                    \
    {                                                                           \
        const int j0 = (JC) * 64;                                               \
        /* V fragment loads for this chunk (consumed after softmax) */          \
        bf16x8 vf[8];                                                           \
        _Pragma("unroll")                                                       \
        for (int mt = 0; mt < 4; ++mt) {                                        \
            vf[mt * 2]     = *(const bf16x8*)(vbase + (size_t)mt * (16 * HW) + j0);      \
            vf[mt * 2 + 1] = *(const bf16x8*)(vbase + (size_t)mt * (16 * HW) + j0 + 32); \
        }                                                                       \
        /* S^T tiles */                                                         \
        f32x4 s[4];                                                             \
        __builtin_amdgcn_s_setprio(1);                                          \
        s[0] = __builtin_amdgcn_mfma_f32_16x16x32_bf16(KA0, qfrag, (f32x4){0.f,0.f,0.f,0.f}, 0, 0, 0); \
        s[1] = __builtin_amdgcn_mfma_f32_16x16x32_bf16(KA1, qfrag, (f32x4){0.f,0.f,0.f,0.f}, 0, 0, 0); \
        s[2] = __builtin_amdgcn_mfma_f32_16x16x32_bf16(KA2, qfrag, (f32x4){0.f,0.f,0.f,0.f}, 0, 0, 0); \
        s[3] = __builtin_amdgcn_mfma_f32_16x16x32_bf16(KA3, qfrag, (f32x4){0.f,0.f,0.f,0.f}, 0, 0, 0); \
        __builtin_amdgcn_s_setprio(0);                                          \
        /* prefetch K for next chunk (hides under softmax+PV) */                \
        if ((JC) + 1 < jend) {                                                  \
            const u16* kp = kbase + (size_t)(((JC) + 1) * 64 + n) * 16;         \
            KB0 = *(const bf16x8*)(kp);                                         \
            KB1 = *(const bf16x8*)(kp + 256);                                   \
            KB2 = *(const bf16x8*)(kp + 512);                                   \
            KB3 = *(const bf16x8*)(kp + 768);                                   \
        }                                                                       \
        float cmax = -1e30f;                                                    \
        _Pragma("unroll")                                                       \
        for (int mt = 0; mt < 4; ++mt)                                          \
            cmax = fmaxf(cmax, fmaxf(fmaxf(s[mt][0], s[mt][1]),                 \
                                     fmaxf(s[mt][2], s[mt][3])));               \
        cmax = fmaxf(cmax, __shfl_xor(cmax, 16));                               \
        cmax = fmaxf(cmax, __shfl_xor(cmax, 32));                               \
        if (__any(cmax > m + 8.f)) {                                            \
            float mnew  = fmaxf(m, cmax);                                       \
            float scale = __builtin_amdgcn_exp2f(m - mnew);                     \
            l *= scale;                                                         \
            _Pragma("unroll")                                                   \
            for (int mt = 0; mt < 4; ++mt) {                                    \
                oacc[mt][0] *= scale; oacc[mt][1] *= scale;                     \
                oacc[mt][2] *= scale; oacc[mt][3] *= scale;                     \
            }                                                                   \
            m = mnew;                                                           \
        }                                                                       \
        float psum = 0.f;                                                       \
        unsigned pw[4][2];                                                      \
        _Pragma("unroll")                                                       \
        for (int mt = 0; mt < 4; ++mt) {                                        \
            float e0 = __builtin_amdgcn_exp2f(s[mt][0] - m);                    \
            float e1 = __builtin_amdgcn_exp2f(s[mt][1] - m);                    \
            float e2 = __builtin_amdgcn_exp2f(s[mt][2] - m);                    \
            float e3 = __builtin_amdgcn_exp2f(s[mt][3] - m);                    \
            psum += (e0 + e1) + (e2 + e3);                                      \
            pw[mt][0] = cvtpk(e0, e1);                                          \
            pw[mt][1] = cvtpk(e2, e3);                                          \
        }                                                                       \
        l += psum;                                                              \
        _Pragma("unroll")                                                       \
        for (int mt = 0; mt < 4; ++mt)                                          \
            *(uint2*)&Ps[w][n][mt * 16 + quad * 4] = make_uint2(pw[mt][0], pw[mt][1]); \
        asm volatile("s_waitcnt lgkmcnt(0)" ::: "memory");                      \
        __builtin_amdgcn_sched_barrier(0);                                      \
        __builtin_amdgcn_s_setprio(1);                                          \
        _Pragma("unroll")                                                       \
        for (int k0 = 0; k0 < 2; ++k0) {                                        \
            bf16x8 pf = *(const bf16x8*)&Ps[w][n][k0 * 32 + quad * 8];          \
            _Pragma("unroll")                                                   \
            for (int mt = 0; mt < 4; ++mt) {                                    \
                oacc[mt] = __builtin_amdgcn_mfma_f32_16x16x32_bf16(             \
                               vf[mt * 2 + k0], pf, oacc[mt], 0, 0, 0);         \
            }                                                                   \
        }                                                                       \
        __builtin_amdgcn_s_setprio(0);                                          \
    }

    for (int jc = jstart; jc < jend; jc += 2) {
        PAM_BODY(kc0, kc1, kc2, kc3, kn0, kn1, kn2, kn3, jc)
        PAM_BODY(kn0, kn1, kn2, kn3, kc0, kc1, kc2, kc3, jc + 1)
    }
#undef PAM_BODY

    // combine l across quads (m already uniform per query)
    l += __shfl_xor(l, 16);
    l += __shfl_xor(l, 32);
    const float rl = 1.f / l;
#pragma unroll
    for (int mt = 0; mt < 4; ++mt)
#pragma unroll
        for (int r = 0; r < 4; ++r) {
            int c = mt * 16 + quad * 4 + r;
            Opart[(((size_t)p * 8 + b) * FI + c) * HW + i0 + w * 16 + n] =
                f2b(oacc[mt][r] * rl);
        }
    if (quad == 0)
        ((float2*)ml)[((size_t)p * 8 + b) * HW + i0 + w * 16 + n] = make_float2(m, l);
}

// ---------------------------------------------------------------------------
// K4: combine PAM partials + cam apply + psi-conv + BN + sigmoid + x * da
// (ml.x is in log2 units -> exp2 combine)
// ---------------------------------------------------------------------------
__global__ __launch_bounds__(256) void k_final(
    const u16* __restrict__ psiB, const u16* __restrict__ psiLo,
    const float* __restrict__ att,
    const u16* __restrict__ Opart, const float* __restrict__ ml,
    const float* __restrict__ x,
    const float* __restrict__ psiw, const float* __restrict__ psib,
    const float* __restrict__ pg, const float* __restrict__ pbeta,
    const float* __restrict__ pm, const float* __restrict__ pv,
    const float* __restrict__ alpha, const float* __restrict__ camb,
    float* __restrict__ out)
{
    const int tid = threadIdx.x, tx = tid & 63, ty = tid >> 6;
    const int b = blockIdx.y, p0 = blockIdx.x * 64;
    __shared__ float tp[64][65];
    __shared__ float A[64][64];
    __shared__ float Zp[4][64];

#pragma unroll
    for (int r = 0; r < 16; ++r) {
        int c = ty * 16 + r;
        size_t idx = ((size_t)b * FI + c) * HW + p0 + tx;
        tp[c][tx] = b2f(psiB[idx]) + b2f(psiLo[idx]);
        A[c][tx]  = att[((size_t)b * 64 + c) * 64 + tx];
    }
    __syncthreads();

    // flash-decoding combine weights for this pixel (log2-domain m)
    float2 ml0 = ((const float2*)ml)[((size_t)0 * 8 + b) * HW + p0 + tx];
    float2 ml1 = ((const float2*)ml)[((size_t)1 * 8 + b) * HW + p0 + tx];
    float M  = fmaxf(ml0.x, ml1.x);
    float w0 = ml0.y * __builtin_amdgcn_exp2f(ml0.x - M);
    float w1 = ml1.y * __builtin_amdgcn_exp2f(ml1.x - M);
    float winv = 1.f / (w0 + w1);
    w0 *= winv; w1 *= winv;

    const float al = alpha[0], cb = camb[0];
    const int c0 = __builtin_amdgcn_readfirstlane(ty * 16);
    float acc[16];
#pragma unroll
    for (int i = 0; i < 16; ++i) acc[i] = 0.f;
#pragma unroll 16
    for (int d = 0; d < 64; ++d) {
        float v = tp[d][tx];
#pragma unroll
        for (int i = 0; i < 16; ++i) acc[i] += A[c0 + i][d] * v;
    }
    float z = 0.f;
#pragma unroll
    for (int i = 0; i < 16; ++i) {
        int c = c0 + i;
        float ps  = tp[c][tx];
        float cam = cb * acc[i] + ps;
        float oa = w0 * b2f(Opart[(((size_t)0 * 8 + b) * FI + c) * HW + p0 + tx])
                 + w1 * b2f(Opart[(((size_t)1 * 8 + b) * FI + c) * HW + p0 + tx]);
        float pam = al * oa + ps;
        z += psiw[c] * (cam * pam);
    }
    Zp[ty][tx] = z;
    __syncthreads();
    float zt = Zp[0][tx] + Zp[1][tx] + Zp[2][tx] + Zp[3][tx] + psib[0];
    float inv = pg[0] * rsqrtf(pv[0] + EPS);
    float gate = (zt - pm[0]) * inv + pbeta[0];
    float da = 1.f / (1.f + __expf(-gate));

#pragma unroll 8
    for (int r = 0; r < 64; ++r) {
        int cl = ty + 4 * r;
        size_t idx = ((size_t)b * CIN + cl) * HW + p0 + tx;
        out[idx] = x[idx] * da;
    }
}

// ---------------------------------------------------------------------------
extern "C" void kernel_launch(void* const* d_in, const int* in_sizes, int n_in,
                              void* d_out, int out_size, void* d_ws, size_t ws_size,
                              hipStream_t stream)
{
    const float* g     = (const float*)d_in[0];
    const float* x     = (const float*)d_in[1];
    const float* Wg_w  = (const float*)d_in[2];
    const float* Wg_b  = (const float*)d_in[3];
    const float* bng_g = (const float*)d_in[4];
    const float* bng_b = (const float*)d_in[5];
    const float* bng_m = (const float*)d_in[6];
    const float* bng_v = (const float*)d_in[7];
    const float* Wx_w  = (const float*)d_in[8];
    const float* Wx_b  = (const float*)d_in[9];
    const float* bnx_g = (const float*)d_in[10];
    const float* bnx_b = (const float*)d_in[11];
    const float* bnx_m = (const float*)d_in[12];
    const float* bnx_v = (const float*)d_in[13];
    const float* psi_w = (const float*)d_in[14];
    const float* psi_b = (const float*)d_in[15];
    const float* bnp_g = (const float*)d_in[16];
    const float* bnp_b = (const float*)d_in[17];
    const float* bnp_m = (const float*)d_in[18];
    const float* bnp_v = (const float*)d_in[19];
    const float* pb_w  = (const float*)d_in[20];
    const float* pb_b  = (const float*)d_in[21];
    const float* pc_w  = (const float*)d_in[22];
    const float* pc_b  = (const float*)d_in[23];
    const float* pd_w  = (const float*)d_in[24];
    const float* pd_b  = (const float*)d_in[25];
    const float* alpha = (const float*)d_in[26];
    const float* camb  = (const float*)d_in[27];
    float* out = (float*)d_out;

    float* ws   = (float*)d_ws;
    // float-unit offsets. Opart overlays Gp (Gp dead after k_camsm).
    u16*  psiB  = (u16*)(ws);                 // fl [0,       1048576)
    u16*  psiLo = (u16*)(ws + 1048576);       // fl [1048576, 2097152)
    u16*  fbcT  = (u16*)(ws + 2097152);       // fl [2097152, 2359296)
    u16*  fdB   = (u16*)(ws + 2359296);       // fl [2359296, 3407872)
    float* att  = ws + 3407872;               // fl [3407872, 3440640)
    u16*  Wp    = (u16*)(ws + 3440640);       // fl [3440640, 3457024)
    float* Cp   = ws + 3457024;               // fl [3457024, 3457088)
    u16*  Wcat  = (u16*)(ws + 3457088);       // fl [3457088, 3459648)
    float* bcat = ws + 3459648;               // fl [3459648, 3459728)
    float* mlws = ws + 3459744;               // fl [3459744, 3590816)
    float* Gp   = ws + 3590816;               // fl [3590816, 4639392)
    u16*  Opart = (u16*)(ws + 3590816);       // fl [3590816, 5687968) overlay
                                              // total ~22.8 MB

    k_prep<<<dim3(16), 256, 0, stream>>>(Wg_w, Wg_b, bng_g, bng_b, bng_m, bng_v,
                                         Wx_w, Wx_b, bnx_g, bnx_b, bnx_m, bnx_v,
                                         pb_w, pb_b, pc_w, pc_b, pd_w, pd_b,
                                         Wp, Cp, Wcat, bcat);
    k_psi<<<dim3(64, 8), 256, 0, stream>>>(g, x, Wp, Cp, Wcat, bcat,
                                           psiB, psiLo, fbcT, fdB);
    k_gram<<<dim3(32, 8), 256, 0, stream>>>(psiB, psiLo, Gp);
    k_camsm<<<dim3(8, 4), 256, 0, stream>>>(Gp, att);
    k_pam<<<dim3(8, 64, 2), 256, 0, stream>>>(fbcT, fdB, Opart, mlws);
    k_final<<<dim3(64, 8), 256, 0, stream>>>(psiB, psiLo, att, Opart, mlws, x,
                                             psi_w, psi_b, bnp_g, bnp_b, bnp_m, bnp_v,
                                             alpha, camb, out);
}

// Round 4
// 290.195 us; speedup vs baseline: 1.2599x; 1.2599x over previous
//
#include <hip/hip_runtime.h>
#include <hip/hip_bf16.h>
#include <math.h>

// Problem constants
#define BB 8
#define CIN 256
#define FI 64
#define HW 4096
#define C8 8
#define EPS 1e-5f
#define LOG2E 1.4426950408889634f

typedef __attribute__((ext_vector_type(8))) short bf16x8;
typedef __attribute__((ext_vector_type(4))) float f32x4;
typedef unsigned short u16;

static __device__ __forceinline__ u16 f2b(float x) {
    unsigned u = __builtin_bit_cast(unsigned, x);
    return (u16)((u + 0x8000u) >> 16);
}
// single-instruction packed f32->bf16 (RNE)
static __device__ __forceinline__ unsigned cvtpk(float a, float b) {
    unsigned r;
    asm("v_cvt_pk_bf16_f32 %0, %1, %2" : "=v"(r) : "v"(a), "v"(b));
    return r;
}
static __device__ __forceinline__ float b2f(u16 v) {
    return __builtin_bit_cast(float, ((unsigned)v) << 16);
}

// ---------------------------------------------------------------------------
// K0: fold BN into psi-conv weights (Wp bf16 [64][512], Cp fp32[64]) and
// build concatenated PAM weights (Wcat bf16 [80][64], bcat fp32[80]).
// pb rows (fb = PAM query) are pre-scaled by log2(e) so the PAM softmax can
// run in exp2 domain with bare v_exp_f32.
// ---------------------------------------------------------------------------
__global__ __launch_bounds__(256) void k_prep(
    const float* __restrict__ Wg, const float* __restrict__ Wgb,
    const float* __restrict__ gg, const float* __restrict__ gbeta,
    const float* __restrict__ gm, const float* __restrict__ gv,
    const float* __restrict__ Wx, const float* __restrict__ Wxb,
    const float* __restrict__ xg, const float* __restrict__ xbeta,
    const float* __restrict__ xm, const float* __restrict__ xv,
    const float* __restrict__ pbw, const float* __restrict__ pbb,
    const float* __restrict__ pcw, const float* __restrict__ pcb,
    const float* __restrict__ pdw, const float* __restrict__ pdb,
    u16* __restrict__ Wp, float* __restrict__ Cp,
    u16* __restrict__ Wcat, float* __restrict__ bcat)
{
    const int gid = blockIdx.x * 256 + threadIdx.x;
    for (int idx = gid; idx < FI * 512; idx += 4096) {
        int o = idx >> 9, k = idx & 511;
        float s, w;
        if (k < 256) { s = gg[o] * rsqrtf(gv[o] + EPS); w = Wg[o * 256 + k]; }
        else         { s = xg[o] * rsqrtf(xv[o] + EPS); w = Wx[o * 256 + k - 256]; }
        Wp[idx] = f2b(w * s);
    }
    for (int idx = gid; idx < 80 * 64; idx += 4096) {
        int row = idx >> 6, col = idx & 63;
        float w;
        if (row < 8)       w = pbw[row * 64 + col] * LOG2E;   // exp2-domain queries
        else if (row < 16) w = pcw[(row - 8) * 64 + col];
        else               w = pdw[(row - 16) * 64 + col];
        Wcat[idx] = f2b(w);
    }
    if (blockIdx.x == 0) {
        int tid = threadIdx.x;
        if (tid < FI) {
            float ig = gg[tid] * rsqrtf(gv[tid] + EPS);
            float ix = xg[tid] * rsqrtf(xv[tid] + EPS);
            Cp[tid] = (Wgb[tid] - gm[tid]) * ig + gbeta[tid]
                    + (Wxb[tid] - xm[tid]) * ix + xbeta[tid];
        }
        if (tid >= 64 && tid < 144) {
            int r = tid - 64;
            float bv = (r < 8) ? pbb[r] * LOG2E : (r < 16 ? pcb[r - 8] : pdb[r - 16]);
            bcat[r] = bv;
        }
    }
}

// ---------------------------------------------------------------------------
// K1: psi = relu(W' @ cat(g,x) + C) via bf16 MFMA, FUSED with fbcd:
// emits psiB/psiLo bf16 [B][64][4096], fbcT bf16 [B][4096][16],
// fdB bf16 [B][64][4096]. psi^T lives only in LDS.
// grid (64 px-tiles, 8 b) x 256
// ---------------------------------------------------------------------------
__global__ __launch_bounds__(256) void k_psi(
    const float* __restrict__ g, const float* __restrict__ x,
    const u16* __restrict__ Wp, const float* __restrict__ Cp,
    const u16* __restrict__ Wcat, const float* __restrict__ bcat,
    u16* __restrict__ psiB, u16* __restrict__ psiLo,
    u16* __restrict__ fbcT, u16* __restrict__ fdB)
{
    const int tid  = threadIdx.x;
    const int lane = tid & 63;
    const int w    = tid >> 6;
    const int n    = lane & 15;
    const int quad = lane >> 4;
    const int b    = blockIdx.y;
    const int p0   = blockIdx.x * 64;

    __shared__ u16 InT[64][72];   // in: [px][ch]; later psi^T, later Tfd [ch][px]
    __shared__ u16 Tbc[64][16];   // [px][out16]

    f32x4 acc[4];
#pragma unroll
    for (int mt = 0; mt < 4; ++mt) acc[mt] = (f32x4){0.f, 0.f, 0.f, 0.f};

    for (int kc = 0; kc < 8; ++kc) {
        const float* src = (kc < 4) ? g : x;
        const int ch0 = (kc & 3) * 64;
        __syncthreads();
#pragma unroll
        for (int r = 0; r < 4; ++r) {
            int ch = (tid >> 4) + r * 16;
            int px = (tid & 15) * 4;
            float4 v = *(const float4*)&src[((size_t)b * CIN + ch0 + ch) * HW + p0 + px];
            InT[px][ch]     = f2b(v.x);
            InT[px + 1][ch] = f2b(v.y);
            InT[px + 2][ch] = f2b(v.z);
            InT[px + 3][ch] = f2b(v.w);
        }
        __syncthreads();
#pragma unroll
        for (int ks = 0; ks < 2; ++ks) {
            const int kglob = kc * 64 + ks * 32;
            bf16x8 bfrag = *(const bf16x8*)&InT[w * 16 + n][ks * 32 + quad * 8];
#pragma unroll
            for (int mt = 0; mt < 4; ++mt) {
                bf16x8 af = *(const bf16x8*)&Wp[(mt * 16 + n) * 512 + kglob + quad * 8];
                acc[mt] = __builtin_amdgcn_mfma_f32_16x16x32_bf16(
                              af, bfrag, acc[mt], 0, 0, 0);
            }
        }
    }

    // bias + relu; store psiB(hi)+psiLo; build psi^T in InT
    float pv[4][4];
#pragma unroll
    for (int mt = 0; mt < 4; ++mt)
#pragma unroll
        for (int r = 0; r < 4; ++r) {
            int c = mt * 16 + quad * 4 + r;
            float v = acc[mt][r] + Cp[c];
            v = v > 0.f ? v : 0.f;
            pv[mt][r] = v;
            u16 hb = f2b(v);
            size_t idx = ((size_t)b * FI + c) * HW + p0 + w * 16 + n;
            psiB[idx]  = hb;
            psiLo[idx] = f2b(v - b2f(hb));
        }
    __syncthreads();   // staging reads done
#pragma unroll
    for (int mt = 0; mt < 4; ++mt) {
        *(unsigned*)&InT[w * 16 + n][mt * 16 + quad * 4]     = cvtpk(pv[mt][0], pv[mt][1]);
        *(unsigned*)&InT[w * 16 + n][mt * 16 + quad * 4 + 2] = cvtpk(pv[mt][2], pv[mt][3]);
    }
    __syncthreads();

    // fbcd MFMAs: A = psi^T rows (px), B = Wcat (L2-resident)
    f32x4 facc[5];
#pragma unroll
    for (int nt = 0; nt < 5; ++nt) facc[nt] = (f32x4){0.f, 0.f, 0.f, 0.f};
#pragma unroll
    for (int ks = 0; ks < 2; ++ks) {
        bf16x8 af = *(const bf16x8*)&InT[w * 16 + n][ks * 32 + quad * 8];
#pragma unroll
        for (int nt = 0; nt < 5; ++nt) {
            bf16x8 bf = *(const bf16x8*)&Wcat[(nt * 16 + n) * FI + ks * 32 + quad * 8];
            facc[nt] = __builtin_amdgcn_mfma_f32_16x16x32_bf16(af, bf, facc[nt], 0, 0, 0);
        }
    }
    __syncthreads();   // all psi^T reads done; reuse InT as Tfd [ch][px]

    {
        float bias = bcat[n];
#pragma unroll
        for (int r = 0; r < 4; ++r)
            Tbc[w * 16 + quad * 4 + r][n] = f2b(facc[0][r] + bias);
    }
#pragma unroll
    for (int nt = 1; nt < 5; ++nt) {
        int ch = (nt - 1) * 16 + n;
        float bias = bcat[nt * 16 + n];
        *(unsigned*)&InT[ch][w * 16 + quad * 4]     = cvtpk(facc[nt][0] + bias, facc[nt][1] + bias);
        *(unsigned*)&InT[ch][w * 16 + quad * 4 + 2] = cvtpk(facc[nt][2] + bias, facc[nt][3] + bias);
    }
    __syncthreads();
    {   // fbcT: 64 rows x 16 el
        int row = tid >> 2, part = tid & 3;
        uint2 v = *(const uint2*)&Tbc[row][part * 4];
        *(uint2*)&fbcT[((size_t)b * HW + p0 + row) * 16 + part * 4] = v;
    }
#pragma unroll
    for (int rep = 0; rep < 2; ++rep) {   // fdB: 64 ch x 64 px
        int t = rep * 256 + tid;
        int ch = t >> 3, seg = t & 7;
        bf16x8 v = *(const bf16x8*)&InT[ch][seg * 8];
        *(bf16x8*)&fdB[((size_t)b * FI + ch) * HW + p0 + seg * 8] = v;
    }
}

// ---------------------------------------------------------------------------
// K3a: Gram partials via compensated bf16 MFMA (hi*hi + hi*lo + lo*hi).
// grid (32 slices, 8 b) x 256 -> Gp[s][b][64][64]
// ---------------------------------------------------------------------------
__global__ __launch_bounds__(256) void k_gram(
    const u16* __restrict__ psiB, const u16* __restrict__ psiLo,
    float* __restrict__ Gp)
{
    const int tid  = threadIdx.x;
    const int lane = tid & 63;
    const int w    = tid >> 6;
    const int n    = lane & 15;
    const int quad = lane >> 4;
    const int s    = blockIdx.x;
    const int b    = blockIdx.y;

    f32x4 acc[4];
#pragma unroll
    for (int nt = 0; nt < 4; ++nt) acc[nt] = (f32x4){0.f, 0.f, 0.f, 0.f};

    for (int ks = 0; ks < 4; ++ks) {
        const int k0 = s * 128 + ks * 32;
        const size_t ra = ((size_t)b * FI + w * 16 + n) * HW + k0 + quad * 8;
        bf16x8 ah = *(const bf16x8*)&psiB[ra];
        bf16x8 al = *(const bf16x8*)&psiLo[ra];
#pragma unroll
        for (int nt = 0; nt < 4; ++nt) {
            const size_t rb = ((size_t)b * FI + nt * 16 + n) * HW + k0 + quad * 8;
            bf16x8 bh = *(const bf16x8*)&psiB[rb];
            bf16x8 bl = *(const bf16x8*)&psiLo[rb];
            acc[nt] = __builtin_amdgcn_mfma_f32_16x16x32_bf16(ah, bh, acc[nt], 0, 0, 0);
            acc[nt] = __builtin_amdgcn_mfma_f32_16x16x32_bf16(ah, bl, acc[nt], 0, 0, 0);
            acc[nt] = __builtin_amdgcn_mfma_f32_16x16x32_bf16(al, bh, acc[nt], 0, 0, 0);
        }
    }
#pragma unroll
    for (int nt = 0; nt < 4; ++nt)
#pragma unroll
        for (int r = 0; r < 4; ++r) {
            int i = w * 16 + quad * 4 + r;
            Gp[(((size_t)s * 8 + b) * 64 + i) * 64 + nt * 16 + n] = acc[nt][r];
        }
}

// ---------------------------------------------------------------------------
// K3b: CAM softmax of (rowmax - G).  grid (8 b, 4 grp) x 256
// ---------------------------------------------------------------------------
__global__ __launch_bounds__(256) void k_camsm(
    const float* __restrict__ Gp, float* __restrict__ att)
{
    const int tid = threadIdx.x, d = tid & 63, ty = tid >> 6;
    const int b = blockIdx.x, grp = blockIdx.y;
#pragma unroll 1
    for (int rr = 0; rr < 4; ++rr) {
        int i = grp * 16 + ty * 4 + rr;
        float gsum = 0.f;
#pragma unroll 1
        for (int s = 0; s < 32; ++s) gsum += Gp[(((size_t)s * 8 + b) * 64 + i) * 64 + d];
        float M = gsum;
#pragma unroll
        for (int msk = 1; msk < 64; msk <<= 1) M = fmaxf(M, __shfl_xor(M, msk));
        float a = M - gsum;
        float m2 = a;
#pragma unroll
        for (int msk = 1; msk < 64; msk <<= 1) m2 = fmaxf(m2, __shfl_xor(m2, msk));
        float p = __expf(a - m2);
        float ssum = p;
#pragma unroll
        for (int msk = 1; msk < 64; msk <<= 1) ssum += __shfl_xor(ssum, msk);
        att[((size_t)b * 64 + i) * 64 + d] = p / ssum;
    }
}

// ---------------------------------------------------------------------------
// K5: PAM flash attention. LDS-staged K/V (cooperative, shared by 4 waves),
// DOUBLE-BUFFERED -> single __syncthreads per key chunk. XOR-swizzled 16B
// slots on Vs/Ps kill the 8-way bank conflicts (rows padded to 128B so row
// contributes 0 to bank; slot ^= row&7 on both write and read).
// Q direct from global (quad 0 real, quads 1-3 zero). exp2-domain softmax,
// defer-rescale (THR=8), cvt_pk packing, setprio around MFMA clusters.
// grid (8 b, 64 qtile, 2 part) x 256. Emits normalized bf16 partials
// Opart[p][b][c][pix] + ml[p][b][pix] = (m, l)   (m in log2 units).
// ---------------------------------------------------------------------------
__global__ __launch_bounds__(256) void k_pam(
    const u16* __restrict__ fbcT, const u16* __restrict__ fdB,
    u16* __restrict__ Opart, float* __restrict__ ml)
{
    const int tid  = threadIdx.x;
    const int lane = tid & 63;
    const int w    = tid >> 6;
    const int n    = lane & 15;
    const int quad = lane >> 4;
    const int b    = blockIdx.x;
    const int i0   = blockIdx.y * 64;
    const int p    = blockIdx.z;
    const int jstart = p * 32, jend = jstart + 32;

    __shared__ u16 Ks[2][68][8];    // [buf][key][k0..7]; rows 64..67 zero pad
    __shared__ u16 Vs[2][64][64];   // [buf][chan][key], 128B rows, swizzled slots
    __shared__ u16 Ps[4][16][64];   // per-wave P^T [q_local][key], swizzled slots

    // zero Ks pad rows (both buffers) once
    if (tid < 16) {
        ((unsigned*)&Ks[0][64][0])[tid] = 0u;
        ((unsigned*)&Ks[1][64][0])[tid] = 0u;
    }

    // Q fragment direct from global: quad 0 = fb (8 dims), quads 1-3 zero.
    bf16x8 qfrag = {};
    if (quad == 0)
        qfrag = *(const bf16x8*)&fbcT[((size_t)b * HW + i0 + w * 16 + n) * 16];

    const int kkey = tid >> 1, khalf = tid & 1;
    const int vch  = tid >> 3, vseg  = tid & 7;
    const int vslot = (vseg ^ (vch & 7)) << 3;   // swizzled u16 col for V writes
    const int pswz  = n & 7;                     // row-XOR for Vs/Ps reads + Ps writes

    // running pointers for prefetch
    const u16* kp = fbcT + ((size_t)b * HW + jstart * 64) * 16 + 8;
    const u16* vp = fdB + (size_t)b * FI * HW + jstart * 64;

    // prefetch chunk jstart into regs
    uint2 kreg = make_uint2(0u, 0u);
    bf16x8 vreg0, vreg1;
    if (tid < 128) kreg = *(const uint2*)(kp + (size_t)kkey * 16 + khalf * 4);
    vreg0 = *(const bf16x8*)(vp + (size_t)vch * HW + vseg * 8);
    vreg1 = *(const bf16x8*)(vp + (size_t)(32 + vch) * HW + vseg * 8);

    f32x4 oacc[4];
#pragma unroll
    for (int mt = 0; mt < 4; ++mt) oacc[mt] = (f32x4){0.f, 0.f, 0.f, 0.f};
    float m = -1e30f, l = 0.f;   // l = per-lane partial (this quad's keys)

    int cur = 0;
    for (int jc = jstart; jc < jend; ++jc) {
        // stage prefetched regs into buffer `cur` (other buffer's readers
        // finished before the PREVIOUS barrier -> safe without a 2nd barrier)
        if (tid < 128) *(uint2*)&Ks[cur][kkey][khalf * 4] = kreg;
        *(bf16x8*)&Vs[cur][vch][vslot]      = vreg0;
        *(bf16x8*)&Vs[cur][32 + vch][vslot] = vreg1;
        if (jc + 1 < jend) {   // prefetch next chunk (lands during compute)
            kp += 64 * 16;
            vp += 64;
            if (tid < 128) kreg = *(const uint2*)(kp + (size_t)kkey * 16 + khalf * 4);
            vreg0 = *(const bf16x8*)(vp + (size_t)vch * HW + vseg * 8);
            vreg1 = *(const bf16x8*)(vp + (size_t)(32 + vch) * HW + vseg * 8);
        }
        __syncthreads();

        // S^T tiles (quad overread hits zero pad rows x zero Q cols)
        f32x4 s[4];
        __builtin_amdgcn_s_setprio(1);
#pragma unroll
        for (int mt = 0; mt < 4; ++mt) {
            bf16x8 af = *(const bf16x8*)&Ks[cur][mt * 16 + n + quad][0];
            s[mt] = __builtin_amdgcn_mfma_f32_16x16x32_bf16(
                        af, qfrag, (f32x4){0.f, 0.f, 0.f, 0.f}, 0, 0, 0);
        }
        __builtin_amdgcn_s_setprio(0);

        float cmax = -1e30f;
#pragma unroll
        for (int mt = 0; mt < 4; ++mt)
            cmax = fmaxf(cmax, fmaxf(fmaxf(s[mt][0], s[mt][1]),
                                     fmaxf(s[mt][2], s[mt][3])));
        cmax = fmaxf(cmax, __shfl_xor(cmax, 16));
        cmax = fmaxf(cmax, __shfl_xor(cmax, 32));

        // defer-rescale: only rescale when max grew by > 8 (exp2 domain,
        // so P is bounded by 2^8 = 256 — safe in bf16)
        if (__any(cmax > m + 8.f)) {
            float mnew  = fmaxf(m, cmax);
            float scale = __builtin_amdgcn_exp2f(m - mnew);
            l *= scale;
#pragma unroll
            for (int mt = 0; mt < 4; ++mt) {
                oacc[mt][0] *= scale; oacc[mt][1] *= scale;
                oacc[mt][2] *= scale; oacc[mt][3] *= scale;
            }
            m = mnew;
        }

        float psum = 0.f;
        unsigned pw[4][2];
#pragma unroll
        for (int mt = 0; mt < 4; ++mt) {
            float e0 = __builtin_amdgcn_exp2f(s[mt][0] - m);
            float e1 = __builtin_amdgcn_exp2f(s[mt][1] - m);
            float e2 = __builtin_amdgcn_exp2f(s[mt][2] - m);
            float e3 = __builtin_amdgcn_exp2f(s[mt][3] - m);
            psum += (e0 + e1) + (e2 + e3);
            pw[mt][0] = cvtpk(e0, e1);
            pw[mt][1] = cvtpk(e2, e3);
        }
        l += psum;

        // Ps write: 16B slot = mt*2 + (quad>>1), swizzled by n&7; 8B half = quad&1
#pragma unroll
        for (int mt = 0; mt < 4; ++mt) {
            int so = (((mt * 2 + (quad >> 1)) ^ pswz) << 3) + ((quad & 1) << 2);
            *(uint2*)&Ps[w][n][so] = make_uint2(pw[mt][0], pw[mt][1]);
        }
        asm volatile("s_waitcnt lgkmcnt(0)" ::: "memory");
        __builtin_amdgcn_sched_barrier(0);

        __builtin_amdgcn_s_setprio(1);
#pragma unroll
        for (int k0 = 0; k0 < 2; ++k0) {
            bf16x8 pf = *(const bf16x8*)&Ps[w][n][((k0 * 4 + quad) ^ pswz) << 3];
#pragma unroll
            for (int mt = 0; mt < 4; ++mt) {
                bf16x8 vf = *(const bf16x8*)
                    &Vs[cur][mt * 16 + n][((k0 * 4 + quad) ^ pswz) << 3];
                oacc[mt] = __builtin_amdgcn_mfma_f32_16x16x32_bf16(
                               vf, pf, oacc[mt], 0, 0, 0);
            }
        }
        __builtin_amdgcn_s_setprio(0);
        cur ^= 1;
    }

    // combine l across quads (m already uniform per query)
    l += __shfl_xor(l, 16);
    l += __shfl_xor(l, 32);
    const float rl = 1.f / l;
#pragma unroll
    for (int mt = 0; mt < 4; ++mt)
#pragma unroll
        for (int r = 0; r < 4; ++r) {
            int c = mt * 16 + quad * 4 + r;
            Opart[(((size_t)p * 8 + b) * FI + c) * HW + i0 + w * 16 + n] =
                f2b(oacc[mt][r] * rl);
        }
    if (quad == 0)
        ((float2*)ml)[((size_t)p * 8 + b) * HW + i0 + w * 16 + n] = make_float2(m, l);
}

// ---------------------------------------------------------------------------
// K4: combine PAM partials + cam apply + psi-conv + BN + sigmoid + x * da
// (ml.x is in log2 units -> exp2 combine)
// ---------------------------------------------------------------------------
__global__ __launch_bounds__(256) void k_final(
    const u16* __restrict__ psiB, const u16* __restrict__ psiLo,
    const float* __restrict__ att,
    const u16* __restrict__ Opart, const float* __restrict__ ml,
    const float* __restrict__ x,
    const float* __restrict__ psiw, const float* __restrict__ psib,
    const float* __restrict__ pg, const float* __restrict__ pbeta,
    const float* __restrict__ pm, const float* __restrict__ pv,
    const float* __restrict__ alpha, const float* __restrict__ camb,
    float* __restrict__ out)
{
    const int tid = threadIdx.x, tx = tid & 63, ty = tid >> 6;
    const int b = blockIdx.y, p0 = blockIdx.x * 64;
    __shared__ float tp[64][65];
    __shared__ float A[64][64];
    __shared__ float Zp[4][64];

#pragma unroll
    for (int r = 0; r < 16; ++r) {
        int c = ty * 16 + r;
        size_t idx = ((size_t)b * FI + c) * HW + p0 + tx;
        tp[c][tx] = b2f(psiB[idx]) + b2f(psiLo[idx]);
        A[c][tx]  = att[((size_t)b * 64 + c) * 64 + tx];
    }
    __syncthreads();

    // flash-decoding combine weights for this pixel (log2-domain m)
    float2 ml0 = ((const float2*)ml)[((size_t)0 * 8 + b) * HW + p0 + tx];
    float2 ml1 = ((const float2*)ml)[((size_t)1 * 8 + b) * HW + p0 + tx];
    float M  = fmaxf(ml0.x, ml1.x);
    float w0 = ml0.y * __builtin_amdgcn_exp2f(ml0.x - M);
    float w1 = ml1.y * __builtin_amdgcn_exp2f(ml1.x - M);
    float winv = 1.f / (w0 + w1);
    w0 *= winv; w1 *= winv;

    const float al = alpha[0], cb = camb[0];
    const int c0 = __builtin_amdgcn_readfirstlane(ty * 16);
    float acc[16];
#pragma unroll
    for (int i = 0; i < 16; ++i) acc[i] = 0.f;
#pragma unroll 16
    for (int d = 0; d < 64; ++d) {
        float v = tp[d][tx];
#pragma unroll
        for (int i = 0; i < 16; ++i) acc[i] += A[c0 + i][d] * v;
    }
    float z = 0.f;
#pragma unroll
    for (int i = 0; i < 16; ++i) {
        int c = c0 + i;
        float ps  = tp[c][tx];
        float cam = cb * acc[i] + ps;
        float oa = w0 * b2f(Opart[(((size_t)0 * 8 + b) * FI + c) * HW + p0 + tx])
                 + w1 * b2f(Opart[(((size_t)1 * 8 + b) * FI + c) * HW + p0 + tx]);
        float pam = al * oa + ps;
        z += psiw[c] * (cam * pam);
    }
    Zp[ty][tx] = z;
    __syncthreads();
    float zt = Zp[0][tx] + Zp[1][tx] + Zp[2][tx] + Zp[3][tx] + psib[0];
    float inv = pg[0] * rsqrtf(pv[0] + EPS);
    float gate = (zt - pm[0]) * inv + pbeta[0];
    float da = 1.f / (1.f + __expf(-gate));

#pragma unroll 8
    for (int r = 0; r < 64; ++r) {
        int cl = ty + 4 * r;
        size_t idx = ((size_t)b * CIN + cl) * HW + p0 + tx;
        out[idx] = x[idx] * da;
    }
}

// ---------------------------------------------------------------------------
extern "C" void kernel_launch(void* const* d_in, const int* in_sizes, int n_in,
                              void* d_out, int out_size, void* d_ws, size_t ws_size,
                              hipStream_t stream)
{
    const float* g     = (const float*)d_in[0];
    const float* x     = (const float*)d_in[1];
    const float* Wg_w  = (const float*)d_in[2];
    const float* Wg_b  = (const float*)d_in[3];
    const float* bng_g = (const float*)d_in[4];
    const float* bng_b = (const float*)d_in[5];
    const float* bng_m = (const float*)d_in[6];
    const float* bng_v = (const float*)d_in[7];
    const float* Wx_w  = (const float*)d_in[8];
    const float* Wx_b  = (const float*)d_in[9];
    const float* bnx_g = (const float*)d_in[10];
    const float* bnx_b = (const float*)d_in[11];
    const float* bnx_m = (const float*)d_in[12];
    const float* bnx_v = (const float*)d_in[13];
    const float* psi_w = (const float*)d_in[14];
    const float* psi_b = (const float*)d_in[15];
    const float* bnp_g = (const float*)d_in[16];
    const float* bnp_b = (const float*)d_in[17];
    const float* bnp_m = (const float*)d_in[18];
    const float* bnp_v = (const float*)d_in[19];
    const float* pb_w  = (const float*)d_in[20];
    const float* pb_b  = (const float*)d_in[21];
    const float* pc_w  = (const float*)d_in[22];
    const float* pc_b  = (const float*)d_in[23];
    const float* pd_w  = (const float*)d_in[24];
    const float* pd_b  = (const float*)d_in[25];
    const float* alpha = (const float*)d_in[26];
    const float* camb  = (const float*)d_in[27];
    float* out = (float*)d_out;

    float* ws   = (float*)d_ws;
    // float-unit offsets. Opart overlays Gp (Gp dead after k_camsm).
    u16*  psiB  = (u16*)(ws);                 // fl [0,       1048576)
    u16*  psiLo = (u16*)(ws + 1048576);       // fl [1048576, 2097152)
    u16*  fbcT  = (u16*)(ws + 2097152);       // fl [2097152, 2359296)
    u16*  fdB   = (u16*)(ws + 2359296);       // fl [2359296, 3407872)
    float* att  = ws + 3407872;               // fl [3407872, 3440640)
    u16*  Wp    = (u16*)(ws + 3440640);       // fl [3440640, 3457024)
    float* Cp   = ws + 3457024;               // fl [3457024, 3457088)
    u16*  Wcat  = (u16*)(ws + 3457088);       // fl [3457088, 3459648)
    float* bcat = ws + 3459648;               // fl [3459648, 3459728)
    float* mlws = ws + 3459744;               // fl [3459744, 3590816)
    float* Gp   = ws + 3590816;               // fl [3590816, 4639392)
    u16*  Opart = (u16*)(ws + 3590816);       // fl [3590816, 5687968) overlay
                                              // total ~22.8 MB

    k_prep<<<dim3(16), 256, 0, stream>>>(Wg_w, Wg_b, bng_g, bng_b, bng_m, bng_v,
                                         Wx_w, Wx_b, bnx_g, bnx_b, bnx_m, bnx_v,
                                         pb_w, pb_b, pc_w, pc_b, pd_w, pd_b,
                                         Wp, Cp, Wcat, bcat);
    k_psi<<<dim3(64, 8), 256, 0, stream>>>(g, x, Wp, Cp, Wcat, bcat,
                                           psiB, psiLo, fbcT, fdB);
    k_gram<<<dim3(32, 8), 256, 0, stream>>>(psiB, psiLo, Gp);
    k_camsm<<<dim3(8, 4), 256, 0, stream>>>(Gp, att);
    k_pam<<<dim3(8, 64, 2), 256, 0, stream>>>(fbcT, fdB, Opart, mlws);
    k_final<<<dim3(64, 8), 256, 0, stream>>>(psiB, psiLo, att, Opart, mlws, x,
                                             psi_w, psi_b, bnp_g, bnp_b, bnp_m, bnp_v,
                                             alpha, camb, out);
}

// Round 6
// 247.818 us; speedup vs baseline: 1.4753x; 1.1710x over previous
//
#include <hip/hip_runtime.h>
#include <hip/hip_bf16.h>
#include <math.h>

// Problem constants
#define BB 8
#define CIN 256
#define FI 64
#define HW 4096
#define C8 8
#define EPS 1e-5f
#define LOG2E 1.4426950408889634f

typedef __attribute__((ext_vector_type(8))) short bf16x8;
typedef __attribute__((ext_vector_type(4))) float f32x4;
typedef unsigned short u16;

static __device__ __forceinline__ u16 f2b(float x) {
    unsigned u = __builtin_bit_cast(unsigned, x);
    return (u16)((u + 0x8000u) >> 16);
}
// single-instruction packed f32->bf16 (RNE)
static __device__ __forceinline__ unsigned cvtpk(float a, float b) {
    unsigned r;
    asm("v_cvt_pk_bf16_f32 %0, %1, %2" : "=v"(r) : "v"(a), "v"(b));
    return r;
}
static __device__ __forceinline__ float b2f(u16 v) {
    return __builtin_bit_cast(float, ((unsigned)v) << 16);
}

// ---------------------------------------------------------------------------
// K0: fold BN into psi-conv weights (Wp bf16 [64][512], Cp fp32[64]) and
// build concatenated PAM weights (Wcat bf16 [80][64], bcat fp32[80]).
// pb rows (fb = PAM query) are pre-scaled by log2(e) so the PAM softmax can
// run in exp2 domain with bare v_exp_f32.
// ---------------------------------------------------------------------------
__global__ __launch_bounds__(256) void k_prep(
    const float* __restrict__ Wg, const float* __restrict__ Wgb,
    const float* __restrict__ gg, const float* __restrict__ gbeta,
    const float* __restrict__ gm, const float* __restrict__ gv,
    const float* __restrict__ Wx, const float* __restrict__ Wxb,
    const float* __restrict__ xg, const float* __restrict__ xbeta,
    const float* __restrict__ xm, const float* __restrict__ xv,
    const float* __restrict__ pbw, const float* __restrict__ pbb,
    const float* __restrict__ pcw, const float* __restrict__ pcb,
    const float* __restrict__ pdw, const float* __restrict__ pdb,
    u16* __restrict__ Wp, float* __restrict__ Cp,
    u16* __restrict__ Wcat, float* __restrict__ bcat)
{
    const int gid = blockIdx.x * 256 + threadIdx.x;
    for (int idx = gid; idx < FI * 512; idx += 4096) {
        int o = idx >> 9, k = idx & 511;
        float s, w;
        if (k < 256) { s = gg[o] * rsqrtf(gv[o] + EPS); w = Wg[o * 256 + k]; }
        else         { s = xg[o] * rsqrtf(xv[o] + EPS); w = Wx[o * 256 + k - 256]; }
        Wp[idx] = f2b(w * s);
    }
    for (int idx = gid; idx < 80 * 64; idx += 4096) {
        int row = idx >> 6, col = idx & 63;
        float w;
        if (row < 8)       w = pbw[row * 64 + col] * LOG2E;   // exp2-domain queries
        else if (row < 16) w = pcw[(row - 8) * 64 + col];
        else               w = pdw[(row - 16) * 64 + col];
        Wcat[idx] = f2b(w);
    }
    if (blockIdx.x == 0) {
        int tid = threadIdx.x;
        if (tid < FI) {
            float ig = gg[tid] * rsqrtf(gv[tid] + EPS);
            float ix = xg[tid] * rsqrtf(xv[tid] + EPS);
            Cp[tid] = (Wgb[tid] - gm[tid]) * ig + gbeta[tid]
                    + (Wxb[tid] - xm[tid]) * ix + xbeta[tid];
        }
        if (tid >= 64 && tid < 144) {
            int r = tid - 64;
            float bv = (r < 8) ? pbb[r] * LOG2E : (r < 16 ? pcb[r - 8] : pdb[r - 16]);
            bcat[r] = bv;
        }
    }
}

// ---------------------------------------------------------------------------
// K1: psi = relu(W' @ cat(g,x) + C) via bf16 MFMA, FUSED with fbcd:
// emits psiB/psiLo bf16 [B][64][4096], fbcT bf16 [B][4096][16],
// fdB bf16 [B][64][4096]. psi^T lives only in LDS.
// grid (64 px-tiles, 8 b) x 256
// ---------------------------------------------------------------------------
__global__ __launch_bounds__(256) void k_psi(
    const float* __restrict__ g, const float* __restrict__ x,
    const u16* __restrict__ Wp, const float* __restrict__ Cp,
    const u16* __restrict__ Wcat, const float* __restrict__ bcat,
    u16* __restrict__ psiB, u16* __restrict__ psiLo,
    u16* __restrict__ fbcT, u16* __restrict__ fdB)
{
    const int tid  = threadIdx.x;
    const int lane = tid & 63;
    const int w    = tid >> 6;
    const int n    = lane & 15;
    const int quad = lane >> 4;
    const int b    = blockIdx.y;
    const int p0   = blockIdx.x * 64;

    __shared__ u16 InT[64][72];   // in: [px][ch]; later psi^T, later Tfd [ch][px]
    __shared__ u16 Tbc[64][16];   // [px][out16]

    f32x4 acc[4];
#pragma unroll
    for (int mt = 0; mt < 4; ++mt) acc[mt] = (f32x4){0.f, 0.f, 0.f, 0.f};

    for (int kc = 0; kc < 8; ++kc) {
        const float* src = (kc < 4) ? g : x;
        const int ch0 = (kc & 3) * 64;
        __syncthreads();
#pragma unroll
        for (int r = 0; r < 4; ++r) {
            int ch = (tid >> 4) + r * 16;
            int px = (tid & 15) * 4;
            float4 v = *(const float4*)&src[((size_t)b * CIN + ch0 + ch) * HW + p0 + px];
            InT[px][ch]     = f2b(v.x);
            InT[px + 1][ch] = f2b(v.y);
            InT[px + 2][ch] = f2b(v.z);
            InT[px + 3][ch] = f2b(v.w);
        }
        __syncthreads();
#pragma unroll
        for (int ks = 0; ks < 2; ++ks) {
            const int kglob = kc * 64 + ks * 32;
            bf16x8 bfrag = *(const bf16x8*)&InT[w * 16 + n][ks * 32 + quad * 8];
#pragma unroll
            for (int mt = 0; mt < 4; ++mt) {
                bf16x8 af = *(const bf16x8*)&Wp[(mt * 16 + n) * 512 + kglob + quad * 8];
                acc[mt] = __builtin_amdgcn_mfma_f32_16x16x32_bf16(
                              af, bfrag, acc[mt], 0, 0, 0);
            }
        }
    }

    // bias + relu; store psiB(hi)+psiLo; build psi^T in InT
    float pv[4][4];
#pragma unroll
    for (int mt = 0; mt < 4; ++mt)
#pragma unroll
        for (int r = 0; r < 4; ++r) {
            int c = mt * 16 + quad * 4 + r;
            float v = acc[mt][r] + Cp[c];
            v = v > 0.f ? v : 0.f;
            pv[mt][r] = v;
            u16 hb = f2b(v);
            size_t idx = ((size_t)b * FI + c) * HW + p0 + w * 16 + n;
            psiB[idx]  = hb;
            psiLo[idx] = f2b(v - b2f(hb));
        }
    __syncthreads();   // staging reads done
#pragma unroll
    for (int mt = 0; mt < 4; ++mt) {
        *(unsigned*)&InT[w * 16 + n][mt * 16 + quad * 4]     = cvtpk(pv[mt][0], pv[mt][1]);
        *(unsigned*)&InT[w * 16 + n][mt * 16 + quad * 4 + 2] = cvtpk(pv[mt][2], pv[mt][3]);
    }
    __syncthreads();

    // fbcd MFMAs: A = psi^T rows (px), B = Wcat (L2-resident)
    f32x4 facc[5];
#pragma unroll
    for (int nt = 0; nt < 5; ++nt) facc[nt] = (f32x4){0.f, 0.f, 0.f, 0.f};
#pragma unroll
    for (int ks = 0; ks < 2; ++ks) {
        bf16x8 af = *(const bf16x8*)&InT[w * 16 + n][ks * 32 + quad * 8];
#pragma unroll
        for (int nt = 0; nt < 5; ++nt) {
            bf16x8 bf = *(const bf16x8*)&Wcat[(nt * 16 + n) * FI + ks * 32 + quad * 8];
            facc[nt] = __builtin_amdgcn_mfma_f32_16x16x32_bf16(af, bf, facc[nt], 0, 0, 0);
        }
    }
    __syncthreads();   // all psi^T reads done; reuse InT as Tfd [ch][px]

    {
        float bias = bcat[n];
#pragma unroll
        for (int r = 0; r < 4; ++r)
            Tbc[w * 16 + quad * 4 + r][n] = f2b(facc[0][r] + bias);
    }
#pragma unroll
    for (int nt = 1; nt < 5; ++nt) {
        int ch = (nt - 1) * 16 + n;
        float bias = bcat[nt * 16 + n];
        *(unsigned*)&InT[ch][w * 16 + quad * 4]     = cvtpk(facc[nt][0] + bias, facc[nt][1] + bias);
        *(unsigned*)&InT[ch][w * 16 + quad * 4 + 2] = cvtpk(facc[nt][2] + bias, facc[nt][3] + bias);
    }
    __syncthreads();
    {   // fbcT: 64 rows x 16 el
        int row = tid >> 2, part = tid & 3;
        uint2 v = *(const uint2*)&Tbc[row][part * 4];
        *(uint2*)&fbcT[((size_t)b * HW + p0 + row) * 16 + part * 4] = v;
    }
#pragma unroll
    for (int rep = 0; rep < 2; ++rep) {   // fdB: 64 ch x 64 px
        int t = rep * 256 + tid;
        int ch = t >> 3, seg = t & 7;
        bf16x8 v = *(const bf16x8*)&InT[ch][seg * 8];
        *(bf16x8*)&fdB[((size_t)b * FI + ch) * HW + p0 + seg * 8] = v;
    }
}

// ---------------------------------------------------------------------------
// K3a: Gram partials via compensated bf16 MFMA (hi*hi + hi*lo + lo*hi).
// grid (32 slices, 8 b, 2 nt-half) x 256 -> Gp[s][b][64][64]
// (z-split doubles blocks/CU for latency hiding; no storage change)
// ---------------------------------------------------------------------------
__global__ __launch_bounds__(256) void k_gram(
    const u16* __restrict__ psiB, const u16* __restrict__ psiLo,
    float* __restrict__ Gp)
{
    const int tid  = threadIdx.x;
    const int lane = tid & 63;
    const int w    = tid >> 6;
    const int n    = lane & 15;
    const int quad = lane >> 4;
    const int s    = blockIdx.x;
    const int b    = blockIdx.y;
    const int zz   = blockIdx.z;   // nt-half: cols zz*32 .. zz*32+31

    f32x4 acc[2];
#pragma unroll
    for (int nt = 0; nt < 2; ++nt) acc[nt] = (f32x4){0.f, 0.f, 0.f, 0.f};

    for (int ks = 0; ks < 4; ++ks) {
        const int k0 = s * 128 + ks * 32;
        const size_t ra = ((size_t)b * FI + w * 16 + n) * HW + k0 + quad * 8;
        bf16x8 ah = *(const bf16x8*)&psiB[ra];
        bf16x8 al = *(const bf16x8*)&psiLo[ra];
#pragma unroll
        for (int nt = 0; nt < 2; ++nt) {
            const size_t rb = ((size_t)b * FI + zz * 32 + nt * 16 + n) * HW + k0 + quad * 8;
            bf16x8 bh = *(const bf16x8*)&psiB[rb];
            bf16x8 bl = *(const bf16x8*)&psiLo[rb];
            acc[nt] = __builtin_amdgcn_mfma_f32_16x16x32_bf16(ah, bh, acc[nt], 0, 0, 0);
            acc[nt] = __builtin_amdgcn_mfma_f32_16x16x32_bf16(ah, bl, acc[nt], 0, 0, 0);
            acc[nt] = __builtin_amdgcn_mfma_f32_16x16x32_bf16(al, bh, acc[nt], 0, 0, 0);
        }
    }
#pragma unroll
    for (int nt = 0; nt < 2; ++nt)
#pragma unroll
        for (int r = 0; r < 4; ++r) {
            int i = w * 16 + quad * 4 + r;
            Gp[(((size_t)s * 8 + b) * 64 + i) * 64 + zz * 32 + nt * 16 + n] = acc[nt][r];
        }
}

// ---------------------------------------------------------------------------
// K3b: CAM softmax of (rowmax - G).  grid (8 b, 64 row) x 256.
// 4-way parallel s-sum via LDS, then one wave does the softmax trees.
// ---------------------------------------------------------------------------
__global__ __launch_bounds__(256) void k_camsm(
    const float* __restrict__ Gp, float* __restrict__ att)
{
    const int tid = threadIdx.x, tx = tid & 63, ty = tid >> 6;
    const int b = blockIdx.x, i = blockIdx.y;
    __shared__ float part[4][64];

    float gs = 0.f;
#pragma unroll
    for (int j = 0; j < 8; ++j) {
        int s = ty * 8 + j;
        gs += Gp[(((size_t)s * 8 + b) * 64 + i) * 64 + tx];
    }
    part[ty][tx] = gs;
    __syncthreads();
    if (tid < 64) {
        float gsum = part[0][tx] + part[1][tx] + part[2][tx] + part[3][tx];
        float M = gsum;
#pragma unroll
        for (int msk = 1; msk < 64; msk <<= 1) M = fmaxf(M, __shfl_xor(M, msk));
        float a = M - gsum;
        float m2 = a;
#pragma unroll
        for (int msk = 1; msk < 64; msk <<= 1) m2 = fmaxf(m2, __shfl_xor(m2, msk));
        float p = __expf(a - m2);
        float ssum = p;
#pragma unroll
        for (int msk = 1; msk < 64; msk <<= 1) ssum += __shfl_xor(ssum, msk);
        att[((size_t)b * 64 + i) * 64 + tx] = p / ssum;
    }
}

// ---------------------------------------------------------------------------
// K5: PAM flash attention. LDS-staged K/V double-buffered, one barrier/chunk,
// XOR-swizzled Vs/Ps. (unchanged from R4 — control)
// ---------------------------------------------------------------------------
__global__ __launch_bounds__(256) void k_pam(
    const u16* __restrict__ fbcT, const u16* __restrict__ fdB,
    u16* __restrict__ Opart, float* __restrict__ ml)
{
    const int tid  = threadIdx.x;
    const int lane = tid & 63;
    const int w    = tid >> 6;
    const int n    = lane & 15;
    const int quad = lane >> 4;
    const int b    = blockIdx.x;
    const int i0   = blockIdx.y * 64;
    const int p    = blockIdx.z;
    const int jstart = p * 32, jend = jstart + 32;

    __shared__ u16 Ks[2][68][8];    // [buf][key][k0..7]; rows 64..67 zero pad
    __shared__ u16 Vs[2][64][64];   // [buf][chan][key], 128B rows, swizzled slots
    __shared__ u16 Ps[4][16][64];   // per-wave P^T [q_local][key], swizzled slots

    if (tid < 16) {
        ((unsigned*)&Ks[0][64][0])[tid] = 0u;
        ((unsigned*)&Ks[1][64][0])[tid] = 0u;
    }

    bf16x8 qfrag = {};
    if (quad == 0)
        qfrag = *(const bf16x8*)&fbcT[((size_t)b * HW + i0 + w * 16 + n) * 16];

    const int kkey = tid >> 1, khalf = tid & 1;
    const int vch  = tid >> 3, vseg  = tid & 7;
    const int vslot = (vseg ^ (vch & 7)) << 3;
    const int pswz  = n & 7;

    const u16* kp = fbcT + ((size_t)b * HW + jstart * 64) * 16 + 8;
    const u16* vp = fdB + (size_t)b * FI * HW + jstart * 64;

    uint2 kreg = make_uint2(0u, 0u);
    bf16x8 vreg0, vreg1;
    if (tid < 128) kreg = *(const uint2*)(kp + (size_t)kkey * 16 + khalf * 4);
    vreg0 = *(const bf16x8*)(vp + (size_t)vch * HW + vseg * 8);
    vreg1 = *(const bf16x8*)(vp + (size_t)(32 + vch) * HW + vseg * 8);

    f32x4 oacc[4];
#pragma unroll
    for (int mt = 0; mt < 4; ++mt) oacc[mt] = (f32x4){0.f, 0.f, 0.f, 0.f};
    float m = -1e30f, l = 0.f;

    int cur = 0;
    for (int jc = jstart; jc < jend; ++jc) {
        if (tid < 128) *(uint2*)&Ks[cur][kkey][khalf * 4] = kreg;
        *(bf16x8*)&Vs[cur][vch][vslot]      = vreg0;
        *(bf16x8*)&Vs[cur][32 + vch][vslot] = vreg1;
        if (jc + 1 < jend) {
            kp += 64 * 16;
            vp += 64;
            if (tid < 128) kreg = *(const uint2*)(kp + (size_t)kkey * 16 + khalf * 4);
            vreg0 = *(const bf16x8*)(vp + (size_t)vch * HW + vseg * 8);
            vreg1 = *(const bf16x8*)(vp + (size_t)(32 + vch) * HW + vseg * 8);
        }
        __syncthreads();

        f32x4 s[4];
        __builtin_amdgcn_s_setprio(1);
#pragma unroll
        for (int mt = 0; mt < 4; ++mt) {
            bf16x8 af = *(const bf16x8*)&Ks[cur][mt * 16 + n + quad][0];
            s[mt] = __builtin_amdgcn_mfma_f32_16x16x32_bf16(
                        af, qfrag, (f32x4){0.f, 0.f, 0.f, 0.f}, 0, 0, 0);
        }
        __builtin_amdgcn_s_setprio(0);

        float cmax = -1e30f;
#pragma unroll
        for (int mt = 0; mt < 4; ++mt)
            cmax = fmaxf(cmax, fmaxf(fmaxf(s[mt][0], s[mt][1]),
                                     fmaxf(s[mt][2], s[mt][3])));
        cmax = fmaxf(cmax, __shfl_xor(cmax, 16));
        cmax = fmaxf(cmax, __shfl_xor(cmax, 32));

        if (__any(cmax > m + 8.f)) {
            float mnew  = fmaxf(m, cmax);
            float scale = __builtin_amdgcn_exp2f(m - mnew);
            l *= scale;
#pragma unroll
            for (int mt = 0; mt < 4; ++mt) {
                oacc[mt][0] *= scale; oacc[mt][1] *= scale;
                oacc[mt][2] *= scale; oacc[mt][3] *= scale;
            }
            m = mnew;
        }

        float psum = 0.f;
        unsigned pw[4][2];
#pragma unroll
        for (int mt = 0; mt < 4; ++mt) {
            float e0 = __builtin_amdgcn_exp2f(s[mt][0] - m);
            float e1 = __builtin_amdgcn_exp2f(s[mt][1] - m);
            float e2 = __builtin_amdgcn_exp2f(s[mt][2] - m);
            float e3 = __builtin_amdgcn_exp2f(s[mt][3] - m);
            psum += (e0 + e1) + (e2 + e3);
            pw[mt][0] = cvtpk(e0, e1);
            pw[mt][1] = cvtpk(e2, e3);
        }
        l += psum;

#pragma unroll
        for (int mt = 0; mt < 4; ++mt) {
            int so = (((mt * 2 + (quad >> 1)) ^ pswz) << 3) + ((quad & 1) << 2);
            *(uint2*)&Ps[w][n][so] = make_uint2(pw[mt][0], pw[mt][1]);
        }
        asm volatile("s_waitcnt lgkmcnt(0)" ::: "memory");
        __builtin_amdgcn_sched_barrier(0);

        __builtin_amdgcn_s_setprio(1);
#pragma unroll
        for (int k0 = 0; k0 < 2; ++k0) {
            bf16x8 pf = *(const bf16x8*)&Ps[w][n][((k0 * 4 + quad) ^ pswz) << 3];
#pragma unroll
            for (int mt = 0; mt < 4; ++mt) {
                bf16x8 vf = *(const bf16x8*)
                    &Vs[cur][mt * 16 + n][((k0 * 4 + quad) ^ pswz) << 3];
                oacc[mt] = __builtin_amdgcn_mfma_f32_16x16x32_bf16(
                               vf, pf, oacc[mt], 0, 0, 0);
            }
        }
        __builtin_amdgcn_s_setprio(0);
        cur ^= 1;
    }

    l += __shfl_xor(l, 16);
    l += __shfl_xor(l, 32);
    const float rl = 1.f / l;
#pragma unroll
    for (int mt = 0; mt < 4; ++mt)
#pragma unroll
        for (int r = 0; r < 4; ++r) {
            int c = mt * 16 + quad * 4 + r;
            Opart[(((size_t)p * 8 + b) * FI + c) * HW + i0 + w * 16 + n] =
                f2b(oacc[mt][r] * rl);
        }
    if (quad == 0)
        ((float2*)ml)[((size_t)p * 8 + b) * HW + i0 + w * 16 + n] = make_float2(m, l);
}

// ---------------------------------------------------------------------------
// K4: combine PAM partials + cam apply + psi-conv + BN + sigmoid + x * da.
// CAM att-apply (att @ psi) now via compensated bf16 MFMA (att bf16,
// psi hi+lo) with XOR-swizzled LDS — replaces ~1088 ds_read_b32/thread with
// ~18 ds_read_b128. ps / epilogue math stays f32 exact.
// grid (64 px-tiles, 8 b) x 256
// ---------------------------------------------------------------------------
__global__ __launch_bounds__(256) void k_final(
    const u16* __restrict__ psiB, const u16* __restrict__ psiLo,
    const float* __restrict__ att,
    const u16* __restrict__ Opart, const float* __restrict__ ml,
    const float* __restrict__ x,
    const float* __restrict__ psiw, const float* __restrict__ psib,
    const float* __restrict__ pg, const float* __restrict__ pbeta,
    const float* __restrict__ pm, const float* __restrict__ pv,
    const float* __restrict__ alpha, const float* __restrict__ camb,
    float* __restrict__ out)
{
    const int tid  = threadIdx.x;
    const int lane = tid & 63;
    const int w    = tid >> 6;
    const int n    = lane & 15;
    const int quad = lane >> 4;
    const int b = blockIdx.y, p0 = blockIdx.x * 64;

    __shared__ u16 Abf[64][64];    // att bf16, rows=c, swizzled 16B slots
    __shared__ u16 tpB[64][64];    // psi hi, rows=px cols=c, swizzled
    __shared__ u16 tpLo[64][64];   // psi lo
    __shared__ float Wc0[64], Wc1[64], Pw[64], daL[64];
    __shared__ float Zp[4][64];

    // stage A = att (rows c, bf16, swizzled)
    {
        int c = tid >> 2, seg = tid & 3;
        const float* ap = &att[((size_t)b * 64 + c) * 64 + seg * 16];
        float4 v0 = *(const float4*)(ap);
        float4 v1 = *(const float4*)(ap + 4);
        float4 v2 = *(const float4*)(ap + 8);
        float4 v3 = *(const float4*)(ap + 12);
        float vv[16] = {v0.x, v0.y, v0.z, v0.w, v1.x, v1.y, v1.z, v1.w,
                        v2.x, v2.y, v2.z, v2.w, v3.x, v3.y, v3.z, v3.w};
#pragma unroll
        for (int j = 0; j < 8; ++j) {
            int d0 = seg * 16 + j * 2;
            int phys = (((d0 >> 3) ^ (c & 7)) << 3) | (d0 & 7);
            *(unsigned*)&Abf[c][phys] = cvtpk(vv[2 * j], vv[2 * j + 1]);
        }
    }
    // stage tp = psi^T (rows px, cols c; hi/lo; swizzled)
    {
        int px = tid & 63, grp = tid >> 6;
#pragma unroll
        for (int cc = 0; cc < 16; cc += 2) {
            int c = grp * 16 + cc;
            size_t i0 = ((size_t)b * FI + c) * HW + p0 + px;
            unsigned hb = ((unsigned)psiB[i0]) | (((unsigned)psiB[i0 + HW]) << 16);
            unsigned lb = ((unsigned)psiLo[i0]) | (((unsigned)psiLo[i0 + HW]) << 16);
            int phys = (((c >> 3) ^ (px & 7)) << 3) | (c & 7);
            *(unsigned*)&tpB[px][phys]  = hb;
            *(unsigned*)&tpLo[px][phys] = lb;
        }
    }
    if (tid < 64) {
        Pw[tid] = psiw[tid];
        float2 ml0 = ((const float2*)ml)[((size_t)0 * 8 + b) * HW + p0 + tid];
        float2 ml1 = ((const float2*)ml)[((size_t)1 * 8 + b) * HW + p0 + tid];
        float M  = fmaxf(ml0.x, ml1.x);
        float w0 = ml0.y * __builtin_amdgcn_exp2f(ml0.x - M);
        float w1 = ml1.y * __builtin_amdgcn_exp2f(ml1.x - M);
        float winv = 1.f / (w0 + w1);
        Wc0[tid] = w0 * winv; Wc1[tid] = w1 * winv;
    }
    __syncthreads();

    // acc[nt] = (att @ psi)[c = w*16+quad*4+r][px = nt*16+n], compensated
    f32x4 acc[4];
#pragma unroll
    for (int nt = 0; nt < 4; ++nt) acc[nt] = (f32x4){0.f, 0.f, 0.f, 0.f};
#pragma unroll
    for (int ks = 0; ks < 2; ++ks) {
        int arow = w * 16 + n;
        bf16x8 af = *(const bf16x8*)&Abf[arow][((ks * 4 + quad) ^ (arow & 7)) << 3];
#pragma unroll
        for (int nt = 0; nt < 4; ++nt) {
            int brow = nt * 16 + n;
            int boff = ((ks * 4 + quad) ^ (brow & 7)) << 3;
            bf16x8 bh = *(const bf16x8*)&tpB[brow][boff];
            bf16x8 bl = *(const bf16x8*)&tpLo[brow][boff];
            acc[nt] = __builtin_amdgcn_mfma_f32_16x16x32_bf16(af, bh, acc[nt], 0, 0, 0);
            acc[nt] = __builtin_amdgcn_mfma_f32_16x16x32_bf16(af, bl, acc[nt], 0, 0, 0);
        }
    }

    // epilogue: cam/pam/z in f32
    const float al = alpha[0], cb = camb[0];
    float z[4] = {0.f, 0.f, 0.f, 0.f};
#pragma unroll
    for (int nt = 0; nt < 4; ++nt) {
        int px = nt * 16 + n;
        float w0 = Wc0[px], w1 = Wc1[px];
#pragma unroll
        for (int r = 0; r < 4; ++r) {
            int c = w * 16 + quad * 4 + r;
            int phys = (((c >> 3) ^ (px & 7)) << 3) | (c & 7);
            float ps  = b2f(tpB[px][phys]) + b2f(tpLo[px][phys]);
            float cam = cb * acc[nt][r] + ps;
            float oa = w0 * b2f(Opart[(((size_t)0 * 8 + b) * FI + c) * HW + p0 + px])
                     + w1 * b2f(Opart[(((size_t)1 * 8 + b) * FI + c) * HW + p0 + px]);
            float pam = al * oa + ps;
            z[nt] += Pw[c] * (cam * pam);
        }
    }
#pragma unroll
    for (int nt = 0; nt < 4; ++nt) {
        z[nt] += __shfl_xor(z[nt], 16);
        z[nt] += __shfl_xor(z[nt], 32);
    }
    if (quad == 0) {
#pragma unroll
        for (int nt = 0; nt < 4; ++nt) Zp[w][nt * 16 + n] = z[nt];
    }
    __syncthreads();
    if (tid < 64) {
        float zt = Zp[0][tid] + Zp[1][tid] + Zp[2][tid] + Zp[3][tid] + psib[0];
        float inv = pg[0] * rsqrtf(pv[0] + EPS);
        float gate = (zt - pm[0]) * inv + pbeta[0];
        daL[tid] = 1.f / (1.f + __expf(-gate));
    }
    __syncthreads();

    const int tx = lane;
    const float da = daL[tx];
#pragma unroll 8
    for (int r = 0; r < 64; ++r) {
        int cl = w + 4 * r;
        size_t idx = ((size_t)b * CIN + cl) * HW + p0 + tx;
        out[idx] = x[idx] * da;
    }
}

// ---------------------------------------------------------------------------
extern "C" void kernel_launch(void* const* d_in, const int* in_sizes, int n_in,
                              void* d_out, int out_size, void* d_ws, size_t ws_size,
                              hipStream_t stream)
{
    const float* g     = (const float*)d_in[0];
    const float* x     = (const float*)d_in[1];
    const float* Wg_w  = (const float*)d_in[2];
    const float* Wg_b  = (const float*)d_in[3];
    const float* bng_g = (const float*)d_in[4];
    const float* bng_b = (const float*)d_in[5];
    const float* bng_m = (const float*)d_in[6];
    const float* bng_v = (const float*)d_in[7];
    const float* Wx_w  = (const float*)d_in[8];
    const float* Wx_b  = (const float*)d_in[9];
    const float* bnx_g = (const float*)d_in[10];
    const float* bnx_b = (const float*)d_in[11];
    const float* bnx_m = (const float*)d_in[12];
    const float* bnx_v = (const float*)d_in[13];
    const float* psi_w = (const float*)d_in[14];
    const float* psi_b = (const float*)d_in[15];
    const float* bnp_g = (const float*)d_in[16];
    const float* bnp_b = (const float*)d_in[17];
    const float* bnp_m = (const float*)d_in[18];
    const float* bnp_v = (const float*)d_in[19];
    const float* pb_w  = (const float*)d_in[20];
    const float* pb_b  = (const float*)d_in[21];
    const float* pc_w  = (const float*)d_in[22];
    const float* pc_b  = (const float*)d_in[23];
    const float* pd_w  = (const float*)d_in[24];
    const float* pd_b  = (const float*)d_in[25];
    const float* alpha = (const float*)d_in[26];
    const float* camb  = (const float*)d_in[27];
    float* out = (float*)d_out;

    float* ws   = (float*)d_ws;
    // float-unit offsets. Opart overlays Gp (Gp dead after k_camsm).
    u16*  psiB  = (u16*)(ws);                 // fl [0,       1048576)
    u16*  psiLo = (u16*)(ws + 1048576);       // fl [1048576, 2097152)
    u16*  fbcT  = (u16*)(ws + 2097152);       // fl [2097152, 2359296)
    u16*  fdB   = (u16*)(ws + 2359296);       // fl [2359296, 3407872)
    float* att  = ws + 3407872;               // fl [3407872, 3440640)
    u16*  Wp    = (u16*)(ws + 3440640);       // fl [3440640, 3457024)
    float* Cp   = ws + 3457024;               // fl [3457024, 3457088)
    u16*  Wcat  = (u16*)(ws + 3457088);       // fl [3457088, 3459648)
    float* bcat = ws + 3459648;               // fl [3459648, 3459728)
    float* mlws = ws + 3459744;               // fl [3459744, 3590816)
    float* Gp   = ws + 3590816;               // fl [3590816, 4639392)
    u16*  Opart = (u16*)(ws + 3590816);       // fl [3590816, 5687968) overlay
                                              // total ~22.8 MB

    k_prep<<<dim3(16), 256, 0, stream>>>(Wg_w, Wg_b, bng_g, bng_b, bng_m, bng_v,
                                         Wx_w, Wx_b, bnx_g, bnx_b, bnx_m, bnx_v,
                                         pb_w, pb_b, pc_w, pc_b, pd_w, pd_b,
                                         Wp, Cp, Wcat, bcat);
    k_psi<<<dim3(64, 8), 256, 0, stream>>>(g, x, Wp, Cp, Wcat, bcat,
                                           psiB, psiLo, fbcT, fdB);
    k_gram<<<dim3(32, 8, 2), 256, 0, stream>>>(psiB, psiLo, Gp);
    k_camsm<<<dim3(8, 64), 256, 0, stream>>>(Gp, att);
    k_pam<<<dim3(8, 64, 2), 256, 0, stream>>>(fbcT, fdB, Opart, mlws);
    k_final<<<dim3(64, 8), 256, 0, stream>>>(psiB, psiLo, att, Opart, mlws, x,
                                             psi_w, psi_b, bnp_g, bnp_b, bnp_m, bnp_v,
                                             alpha, camb, out);
}

// Round 7
// 244.904 us; speedup vs baseline: 1.4929x; 1.0119x over previous
//
#include <hip/hip_runtime.h>
#include <hip/hip_bf16.h>
#include <math.h>

// Problem constants
#define BB 8
#define CIN 256
#define FI 64
#define HW 4096
#define C8 8
#define EPS 1e-5f
#define LOG2E 1.4426950408889634f

typedef __attribute__((ext_vector_type(8))) short bf16x8;
typedef __attribute__((ext_vector_type(4))) float f32x4;
typedef unsigned short u16;

static __device__ __forceinline__ u16 f2b(float x) {
    unsigned u = __builtin_bit_cast(unsigned, x);
    return (u16)((u + 0x8000u) >> 16);
}
// single-instruction packed f32->bf16 (RNE)
static __device__ __forceinline__ unsigned cvtpk(float a, float b) {
    unsigned r;
    asm("v_cvt_pk_bf16_f32 %0, %1, %2" : "=v"(r) : "v"(a), "v"(b));
    return r;
}
static __device__ __forceinline__ float b2f(u16 v) {
    return __builtin_bit_cast(float, ((unsigned)v) << 16);
}

// ---------------------------------------------------------------------------
// K0: fold BN into psi-conv weights (Wp bf16 [64][512], Cp fp32[64]) and
// build concatenated PAM weights (Wcat bf16 [80][64], bcat fp32[80]).
// pb rows (fb = PAM query) are pre-scaled by log2(e) so the PAM softmax can
// run in exp2 domain with bare v_exp_f32.
// ---------------------------------------------------------------------------
__global__ __launch_bounds__(256) void k_prep(
    const float* __restrict__ Wg, const float* __restrict__ Wgb,
    const float* __restrict__ gg, const float* __restrict__ gbeta,
    const float* __restrict__ gm, const float* __restrict__ gv,
    const float* __restrict__ Wx, const float* __restrict__ Wxb,
    const float* __restrict__ xg, const float* __restrict__ xbeta,
    const float* __restrict__ xm, const float* __restrict__ xv,
    const float* __restrict__ pbw, const float* __restrict__ pbb,
    const float* __restrict__ pcw, const float* __restrict__ pcb,
    const float* __restrict__ pdw, const float* __restrict__ pdb,
    u16* __restrict__ Wp, float* __restrict__ Cp,
    u16* __restrict__ Wcat, float* __restrict__ bcat)
{
    const int gid = blockIdx.x * 256 + threadIdx.x;
    for (int idx = gid; idx < FI * 512; idx += 4096) {
        int o = idx >> 9, k = idx & 511;
        float s, w;
        if (k < 256) { s = gg[o] * rsqrtf(gv[o] + EPS); w = Wg[o * 256 + k]; }
        else         { s = xg[o] * rsqrtf(xv[o] + EPS); w = Wx[o * 256 + k - 256]; }
        Wp[idx] = f2b(w * s);
    }
    for (int idx = gid; idx < 80 * 64; idx += 4096) {
        int row = idx >> 6, col = idx & 63;
        float w;
        if (row < 8)       w = pbw[row * 64 + col] * LOG2E;   // exp2-domain queries
        else if (row < 16) w = pcw[(row - 8) * 64 + col];
        else               w = pdw[(row - 16) * 64 + col];
        Wcat[idx] = f2b(w);
    }
    if (blockIdx.x == 0) {
        int tid = threadIdx.x;
        if (tid < FI) {
            float ig = gg[tid] * rsqrtf(gv[tid] + EPS);
            float ix = xg[tid] * rsqrtf(xv[tid] + EPS);
            Cp[tid] = (Wgb[tid] - gm[tid]) * ig + gbeta[tid]
                    + (Wxb[tid] - xm[tid]) * ix + xbeta[tid];
        }
        if (tid >= 64 && tid < 144) {
            int r = tid - 64;
            float bv = (r < 8) ? pbb[r] * LOG2E : (r < 16 ? pcb[r - 8] : pdb[r - 16]);
            bcat[r] = bv;
        }
    }
}

// ---------------------------------------------------------------------------
// K1: psi = relu(W' @ cat(g,x) + C) via bf16 MFMA, FUSED with fbcd:
// emits psiB/psiLo bf16 [B][64][4096], fbcT bf16 [B][4096][16],
// fdB bf16 [B][64][4096]. psi^T lives only in LDS.
// grid (64 px-tiles, 8 b) x 256
// ---------------------------------------------------------------------------
__global__ __launch_bounds__(256) void k_psi(
    const float* __restrict__ g, const float* __restrict__ x,
    const u16* __restrict__ Wp, const float* __restrict__ Cp,
    const u16* __restrict__ Wcat, const float* __restrict__ bcat,
    u16* __restrict__ psiB, u16* __restrict__ psiLo,
    u16* __restrict__ fbcT, u16* __restrict__ fdB)
{
    const int tid  = threadIdx.x;
    const int lane = tid & 63;
    const int w    = tid >> 6;
    const int n    = lane & 15;
    const int quad = lane >> 4;
    const int b    = blockIdx.y;
    const int p0   = blockIdx.x * 64;

    __shared__ u16 InT[64][72];   // in: [px][ch]; later psi^T, later Tfd [ch][px]
    __shared__ u16 Tbc[64][16];   // [px][out16]

    f32x4 acc[4];
#pragma unroll
    for (int mt = 0; mt < 4; ++mt) acc[mt] = (f32x4){0.f, 0.f, 0.f, 0.f};

    for (int kc = 0; kc < 8; ++kc) {
        const float* src = (kc < 4) ? g : x;
        const int ch0 = (kc & 3) * 64;
        __syncthreads();
#pragma unroll
        for (int r = 0; r < 4; ++r) {
            int ch = (tid >> 4) + r * 16;
            int px = (tid & 15) * 4;
            float4 v = *(const float4*)&src[((size_t)b * CIN + ch0 + ch) * HW + p0 + px];
            InT[px][ch]     = f2b(v.x);
            InT[px + 1][ch] = f2b(v.y);
            InT[px + 2][ch] = f2b(v.z);
            InT[px + 3][ch] = f2b(v.w);
        }
        __syncthreads();
#pragma unroll
        for (int ks = 0; ks < 2; ++ks) {
            const int kglob = kc * 64 + ks * 32;
            bf16x8 bfrag = *(const bf16x8*)&InT[w * 16 + n][ks * 32 + quad * 8];
#pragma unroll
            for (int mt = 0; mt < 4; ++mt) {
                bf16x8 af = *(const bf16x8*)&Wp[(mt * 16 + n) * 512 + kglob + quad * 8];
                acc[mt] = __builtin_amdgcn_mfma_f32_16x16x32_bf16(
                              af, bfrag, acc[mt], 0, 0, 0);
            }
        }
    }

    // bias + relu; store psiB(hi)+psiLo; build psi^T in InT
    float pv[4][4];
#pragma unroll
    for (int mt = 0; mt < 4; ++mt)
#pragma unroll
        for (int r = 0; r < 4; ++r) {
            int c = mt * 16 + quad * 4 + r;
            float v = acc[mt][r] + Cp[c];
            v = v > 0.f ? v : 0.f;
            pv[mt][r] = v;
            u16 hb = f2b(v);
            size_t idx = ((size_t)b * FI + c) * HW + p0 + w * 16 + n;
            psiB[idx]  = hb;
            psiLo[idx] = f2b(v - b2f(hb));
        }
    __syncthreads();   // staging reads done
#pragma unroll
    for (int mt = 0; mt < 4; ++mt) {
        *(unsigned*)&InT[w * 16 + n][mt * 16 + quad * 4]     = cvtpk(pv[mt][0], pv[mt][1]);
        *(unsigned*)&InT[w * 16 + n][mt * 16 + quad * 4 + 2] = cvtpk(pv[mt][2], pv[mt][3]);
    }
    __syncthreads();

    // fbcd MFMAs: A = psi^T rows (px), B = Wcat (L2-resident)
    f32x4 facc[5];
#pragma unroll
    for (int nt = 0; nt < 5; ++nt) facc[nt] = (f32x4){0.f, 0.f, 0.f, 0.f};
#pragma unroll
    for (int ks = 0; ks < 2; ++ks) {
        bf16x8 af = *(const bf16x8*)&InT[w * 16 + n][ks * 32 + quad * 8];
#pragma unroll
        for (int nt = 0; nt < 5; ++nt) {
            bf16x8 bf = *(const bf16x8*)&Wcat[(nt * 16 + n) * FI + ks * 32 + quad * 8];
            facc[nt] = __builtin_amdgcn_mfma_f32_16x16x32_bf16(af, bf, facc[nt], 0, 0, 0);
        }
    }
    __syncthreads();   // all psi^T reads done; reuse InT as Tfd [ch][px]

    {
        float bias = bcat[n];
#pragma unroll
        for (int r = 0; r < 4; ++r)
            Tbc[w * 16 + quad * 4 + r][n] = f2b(facc[0][r] + bias);
    }
#pragma unroll
    for (int nt = 1; nt < 5; ++nt) {
        int ch = (nt - 1) * 16 + n;
        float bias = bcat[nt * 16 + n];
        *(unsigned*)&InT[ch][w * 16 + quad * 4]     = cvtpk(facc[nt][0] + bias, facc[nt][1] + bias);
        *(unsigned*)&InT[ch][w * 16 + quad * 4 + 2] = cvtpk(facc[nt][2] + bias, facc[nt][3] + bias);
    }
    __syncthreads();
    {   // fbcT: 64 rows x 16 el
        int row = tid >> 2, part = tid & 3;
        uint2 v = *(const uint2*)&Tbc[row][part * 4];
        *(uint2*)&fbcT[((size_t)b * HW + p0 + row) * 16 + part * 4] = v;
    }
#pragma unroll
    for (int rep = 0; rep < 2; ++rep) {   // fdB: 64 ch x 64 px
        int t = rep * 256 + tid;
        int ch = t >> 3, seg = t & 7;
        bf16x8 v = *(const bf16x8*)&InT[ch][seg * 8];
        *(bf16x8*)&fdB[((size_t)b * FI + ch) * HW + p0 + seg * 8] = v;
    }
}

// ---------------------------------------------------------------------------
// K3a: Gram partials via compensated bf16 MFMA (hi*hi + hi*lo + lo*hi).
// grid (32 slices, 8 b, 2 nt-half) x 256 -> Gp[s][b][64][64]
// ---------------------------------------------------------------------------
__global__ __launch_bounds__(256) void k_gram(
    const u16* __restrict__ psiB, const u16* __restrict__ psiLo,
    float* __restrict__ Gp)
{
    const int tid  = threadIdx.x;
    const int lane = tid & 63;
    const int w    = tid >> 6;
    const int n    = lane & 15;
    const int quad = lane >> 4;
    const int s    = blockIdx.x;
    const int b    = blockIdx.y;
    const int zz   = blockIdx.z;   // nt-half: cols zz*32 .. zz*32+31

    f32x4 acc[2];
#pragma unroll
    for (int nt = 0; nt < 2; ++nt) acc[nt] = (f32x4){0.f, 0.f, 0.f, 0.f};

    for (int ks = 0; ks < 4; ++ks) {
        const int k0 = s * 128 + ks * 32;
        const size_t ra = ((size_t)b * FI + w * 16 + n) * HW + k0 + quad * 8;
        bf16x8 ah = *(const bf16x8*)&psiB[ra];
        bf16x8 al = *(const bf16x8*)&psiLo[ra];
#pragma unroll
        for (int nt = 0; nt < 2; ++nt) {
            const size_t rb = ((size_t)b * FI + zz * 32 + nt * 16 + n) * HW + k0 + quad * 8;
            bf16x8 bh = *(const bf16x8*)&psiB[rb];
            bf16x8 bl = *(const bf16x8*)&psiLo[rb];
            acc[nt] = __builtin_amdgcn_mfma_f32_16x16x32_bf16(ah, bh, acc[nt], 0, 0, 0);
            acc[nt] = __builtin_amdgcn_mfma_f32_16x16x32_bf16(ah, bl, acc[nt], 0, 0, 0);
            acc[nt] = __builtin_amdgcn_mfma_f32_16x16x32_bf16(al, bh, acc[nt], 0, 0, 0);
        }
    }
#pragma unroll
    for (int nt = 0; nt < 2; ++nt)
#pragma unroll
        for (int r = 0; r < 4; ++r) {
            int i = w * 16 + quad * 4 + r;
            Gp[(((size_t)s * 8 + b) * 64 + i) * 64 + zz * 32 + nt * 16 + n] = acc[nt][r];
        }
}

// ---------------------------------------------------------------------------
// K3b: CAM softmax of (rowmax - G).  grid (8 b, 64 row) x 256.
// ---------------------------------------------------------------------------
__global__ __launch_bounds__(256) void k_camsm(
    const float* __restrict__ Gp, float* __restrict__ att)
{
    const int tid = threadIdx.x, tx = tid & 63, ty = tid >> 6;
    const int b = blockIdx.x, i = blockIdx.y;
    __shared__ float part[4][64];

    float gs = 0.f;
#pragma unroll
    for (int j = 0; j < 8; ++j) {
        int s = ty * 8 + j;
        gs += Gp[(((size_t)s * 8 + b) * 64 + i) * 64 + tx];
    }
    part[ty][tx] = gs;
    __syncthreads();
    if (tid < 64) {
        float gsum = part[0][tx] + part[1][tx] + part[2][tx] + part[3][tx];
        float M = gsum;
#pragma unroll
        for (int msk = 1; msk < 64; msk <<= 1) M = fmaxf(M, __shfl_xor(M, msk));
        float a = M - gsum;
        float m2 = a;
#pragma unroll
        for (int msk = 1; msk < 64; msk <<= 1) m2 = fmaxf(m2, __shfl_xor(m2, msk));
        float p = __expf(a - m2);
        float ssum = p;
#pragma unroll
        for (int msk = 1; msk < 64; msk <<= 1) ssum += __shfl_xor(ssum, msk);
        att[((size_t)b * 64 + i) * 64 + tx] = p / ssum;
    }
}

// ---------------------------------------------------------------------------
// K5: PAM flash attention. LDS-staged K/V double-buffered, XOR-swizzled.
// NEW: 2-deep register prefetch (loads issued 2 iterations before LDS-stage
// use -> global latency fully covered), compiler-managed lgkm waits on the
// Ps round-trip, max3 reduction trees.
// grid (8 b, 64 qtile, 2 part) x 256.
// ---------------------------------------------------------------------------
__global__ __launch_bounds__(256) void k_pam(
    const u16* __restrict__ fbcT, const u16* __restrict__ fdB,
    u16* __restrict__ Opart, float* __restrict__ ml)
{
    const int tid  = threadIdx.x;
    const int lane = tid & 63;
    const int w    = tid >> 6;
    const int n    = lane & 15;
    const int quad = lane >> 4;
    const int b    = blockIdx.x;
    const int i0   = blockIdx.y * 64;
    const int p    = blockIdx.z;
    const int jstart = p * 32, jend = jstart + 32;

    __shared__ u16 Ks[2][68][8];    // [buf][key][k0..7]; rows 64..67 zero pad
    __shared__ u16 Vs[2][64][64];   // [buf][chan][key], 128B rows, swizzled slots
    __shared__ u16 Ps[4][16][64];   // per-wave P^T [q_local][key], swizzled slots

    if (tid < 16) {
        ((unsigned*)&Ks[0][64][0])[tid] = 0u;
        ((unsigned*)&Ks[1][64][0])[tid] = 0u;
    }

    bf16x8 qfrag = {};
    if (quad == 0)
        qfrag = *(const bf16x8*)&fbcT[((size_t)b * HW + i0 + w * 16 + n) * 16];

    const int kkey = tid >> 1, khalf = tid & 1;
    const int vch  = tid >> 3, vseg  = tid & 7;
    const int vslot = (vseg ^ (vch & 7)) << 3;
    const int pswz  = n & 7;

    // round-base pointers (chunk jc); set0 = jc, set1 = jc+1 (+1024/+64)
    const u16* kp = fbcT + ((size_t)b * HW + jstart * 64) * 16 + 8;
    const u16* vp = fdB + (size_t)b * FI * HW + jstart * 64;

    // 2-deep prefetch: named register sets (no runtime indexing)
    uint2 kr0 = make_uint2(0u, 0u), kr1 = make_uint2(0u, 0u);
    bf16x8 v0a, v0b, v1a, v1b;
    if (tid < 128) {
        kr0 = *(const uint2*)(kp + (size_t)kkey * 16 + khalf * 4);
        kr1 = *(const uint2*)(kp + 1024 + (size_t)kkey * 16 + khalf * 4);
    }
    v0a = *(const bf16x8*)(vp + (size_t)vch * HW + vseg * 8);
    v0b = *(const bf16x8*)(vp + (size_t)(32 + vch) * HW + vseg * 8);
    v1a = *(const bf16x8*)(vp + 64 + (size_t)vch * HW + vseg * 8);
    v1b = *(const bf16x8*)(vp + 64 + (size_t)(32 + vch) * HW + vseg * 8);

    f32x4 oacc[4];
#pragma unroll
    for (int mt = 0; mt < 4; ++mt) oacc[mt] = (f32x4){0.f, 0.f, 0.f, 0.f};
    float m = -1e30f, l = 0.f;

#define PAM_STEP(BUF)                                                           \
    {                                                                           \
        f32x4 s[4];                                                             \
        __builtin_amdgcn_s_setprio(1);                                          \
        _Pragma("unroll")                                                       \
        for (int mt = 0; mt < 4; ++mt) {                                        \
            bf16x8 af = *(const bf16x8*)&Ks[BUF][mt * 16 + n + quad][0];        \
            s[mt] = __builtin_amdgcn_mfma_f32_16x16x32_bf16(                    \
                        af, qfrag, (f32x4){0.f, 0.f, 0.f, 0.f}, 0, 0, 0);       \
        }                                                                       \
        __builtin_amdgcn_s_setprio(0);                                          \
        /* max3-friendly reduction tree over 16 values */                       \
        float cm = fmaxf(fmaxf(s[0][0], s[0][1]), s[0][2]);                     \
        cm = fmaxf(fmaxf(cm, s[0][3]), s[1][0]);                                \
        cm = fmaxf(fmaxf(cm, s[1][1]), s[1][2]);                                \
        cm = fmaxf(fmaxf(cm, s[1][3]), s[2][0]);                                \
        cm = fmaxf(fmaxf(cm, s[2][1]), s[2][2]);                                \
        cm = fmaxf(fmaxf(cm, s[2][3]), s[3][0]);                                \
        cm = fmaxf(fmaxf(cm, s[3][1]), s[3][2]);                                \
        cm = fmaxf(cm, s[3][3]);                                                \
        cm = fmaxf(cm, __shfl_xor(cm, 16));                                     \
        cm = fmaxf(cm, __shfl_xor(cm, 32));                                     \
        if (__any(cm > m + 8.f)) {                                              \
            float mnew  = fmaxf(m, cm);                                         \
            float scale = __builtin_amdgcn_exp2f(m - mnew);                     \
            l *= scale;                                                         \
            _Pragma("unroll")                                                   \
            for (int mt = 0; mt < 4; ++mt) {                                    \
                oacc[mt][0] *= scale; oacc[mt][1] *= scale;                     \
                oacc[mt][2] *= scale; oacc[mt][3] *= scale;                     \
            }                                                                   \
            m = mnew;                                                           \
        }                                                                       \
        float psum = 0.f;                                                       \
        unsigned pw[4][2];                                                      \
        _Pragma("unroll")                                                       \
        for (int mt = 0; mt < 4; ++mt) {                                        \
            float e0 = __builtin_amdgcn_exp2f(s[mt][0] - m);                    \
            float e1 = __builtin_amdgcn_exp2f(s[mt][1] - m);                    \
            float e2 = __builtin_amdgcn_exp2f(s[mt][2] - m);                    \
            float e3 = __builtin_amdgcn_exp2f(s[mt][3] - m);                    \
            psum += (e0 + e1) + (e2 + e3);                                      \
            pw[mt][0] = cvtpk(e0, e1);                                          \
            pw[mt][1] = cvtpk(e2, e3);                                          \
        }                                                                       \
        l += psum;                                                              \
        _Pragma("unroll")                                                       \
        for (int mt = 0; mt < 4; ++mt) {                                        \
            int so = (((mt * 2 + (quad >> 1)) ^ pswz) << 3) + ((quad & 1) << 2);\
            *(uint2*)&Ps[w][n][so] = make_uint2(pw[mt][0], pw[mt][1]);          \
        }                                                                       \
        __builtin_amdgcn_s_setprio(1);                                          \
        _Pragma("unroll")                                                       \
        for (int k0 = 0; k0 < 2; ++k0) {                                        \
            bf16x8 pf = *(const bf16x8*)&Ps[w][n][((k0 * 4 + quad) ^ pswz) << 3];\
            _Pragma("unroll")                                                   \
            for (int mt = 0; mt < 4; ++mt) {                                    \
                bf16x8 vf = *(const bf16x8*)                                    \
                    &Vs[BUF][mt * 16 + n][((k0 * 4 + quad) ^ pswz) << 3];       \
                oacc[mt] = __builtin_amdgcn_mfma_f32_16x16x32_bf16(             \
                               vf, pf, oacc[mt], 0, 0, 0);                      \
            }                                                                   \
        }                                                                       \
        __builtin_amdgcn_s_setprio(0);                                          \
    }

    for (int jc = jstart; jc < jend; jc += 2) {
        // ---- even phase: buffer 0, set 0 (loaded 2 iterations ago) ----
        if (tid < 128) *(uint2*)&Ks[0][kkey][khalf * 4] = kr0;
        *(bf16x8*)&Vs[0][vch][vslot]      = v0a;
        *(bf16x8*)&Vs[0][32 + vch][vslot] = v0b;
        if (jc + 2 < jend) {   // prefetch chunk jc+2 into set 0
            if (tid < 128)
                kr0 = *(const uint2*)(kp + 2048 + (size_t)kkey * 16 + khalf * 4);
            v0a = *(const bf16x8*)(vp + 128 + (size_t)vch * HW + vseg * 8);
            v0b = *(const bf16x8*)(vp + 128 + (size_t)(32 + vch) * HW + vseg * 8);
        }
        __syncthreads();
        PAM_STEP(0)

        // ---- odd phase: buffer 1, set 1 ----
        if (tid < 128) *(uint2*)&Ks[1][kkey][khalf * 4] = kr1;
        *(bf16x8*)&Vs[1][vch][vslot]      = v1a;
        *(bf16x8*)&Vs[1][32 + vch][vslot] = v1b;
        if (jc + 3 < jend) {   // prefetch chunk jc+3 into set 1
            if (tid < 128)
                kr1 = *(const uint2*)(kp + 3072 + (size_t)kkey * 16 + khalf * 4);
            v1a = *(const bf16x8*)(vp + 192 + (size_t)vch * HW + vseg * 8);
            v1b = *(const bf16x8*)(vp + 192 + (size_t)(32 + vch) * HW + vseg * 8);
        }
        kp += 2048;
        vp += 128;
        __syncthreads();
        PAM_STEP(1)
    }
#undef PAM_STEP

    l += __shfl_xor(l, 16);
    l += __shfl_xor(l, 32);
    const float rl = 1.f / l;
#pragma unroll
    for (int mt = 0; mt < 4; ++mt)
#pragma unroll
        for (int r = 0; r < 4; ++r) {
            int c = mt * 16 + quad * 4 + r;
            Opart[(((size_t)p * 8 + b) * FI + c) * HW + i0 + w * 16 + n] =
                f2b(oacc[mt][r] * rl);
        }
    if (quad == 0)
        ((float2*)ml)[((size_t)p * 8 + b) * HW + i0 + w * 16 + n] = make_float2(m, l);
}

// ---------------------------------------------------------------------------
// K4: combine PAM partials + cam apply + psi-conv + BN + sigmoid + x * da.
// (unchanged from R6)
// ---------------------------------------------------------------------------
__global__ __launch_bounds__(256) void k_final(
    const u16* __restrict__ psiB, const u16* __restrict__ psiLo,
    const float* __restrict__ att,
    const u16* __restrict__ Opart, const float* __restrict__ ml,
    const float* __restrict__ x,
    const float* __restrict__ psiw, const float* __restrict__ psib,
    const float* __restrict__ pg, const float* __restrict__ pbeta,
    const float* __restrict__ pm, const float* __restrict__ pv,
    const float* __restrict__ alpha, const float* __restrict__ camb,
    float* __restrict__ out)
{
    const int tid  = threadIdx.x;
    const int lane = tid & 63;
    const int w    = tid >> 6;
    const int n    = lane & 15;
    const int quad = lane >> 4;
    const int b = blockIdx.y, p0 = blockIdx.x * 64;

    __shared__ u16 Abf[64][64];    // att bf16, rows=c, swizzled 16B slots
    __shared__ u16 tpB[64][64];    // psi hi, rows=px cols=c, swizzled
    __shared__ u16 tpLo[64][64];   // psi lo
    __shared__ float Wc0[64], Wc1[64], Pw[64], daL[64];
    __shared__ float Zp[4][64];

    // stage A = att (rows c, bf16, swizzled)
    {
        int c = tid >> 2, seg = tid & 3;
        const float* ap = &att[((size_t)b * 64 + c) * 64 + seg * 16];
        float4 v0 = *(const float4*)(ap);
        float4 v1 = *(const float4*)(ap + 4);
        float4 v2 = *(const float4*)(ap + 8);
        float4 v3 = *(const float4*)(ap + 12);
        float vv[16] = {v0.x, v0.y, v0.z, v0.w, v1.x, v1.y, v1.z, v1.w,
                        v2.x, v2.y, v2.z, v2.w, v3.x, v3.y, v3.z, v3.w};
#pragma unroll
        for (int j = 0; j < 8; ++j) {
            int d0 = seg * 16 + j * 2;
            int phys = (((d0 >> 3) ^ (c & 7)) << 3) | (d0 & 7);
            *(unsigned*)&Abf[c][phys] = cvtpk(vv[2 * j], vv[2 * j + 1]);
        }
    }
    // stage tp = psi^T (rows px, cols c; hi/lo; swizzled)
    {
        int px = tid & 63, grp = tid >> 6;
#pragma unroll
        for (int cc = 0; cc < 16; cc += 2) {
            int c = grp * 16 + cc;
            size_t i0 = ((size_t)b * FI + c) * HW + p0 + px;
            unsigned hb = ((unsigned)psiB[i0]) | (((unsigned)psiB[i0 + HW]) << 16);
            unsigned lb = ((unsigned)psiLo[i0]) | (((unsigned)psiLo[i0 + HW]) << 16);
            int phys = (((c >> 3) ^ (px & 7)) << 3) | (c & 7);
            *(unsigned*)&tpB[px][phys]  = hb;
            *(unsigned*)&tpLo[px][phys] = lb;
        }
    }
    if (tid < 64) {
        Pw[tid] = psiw[tid];
        float2 ml0 = ((const float2*)ml)[((size_t)0 * 8 + b) * HW + p0 + tid];
        float2 ml1 = ((const float2*)ml)[((size_t)1 * 8 + b) * HW + p0 + tid];
        float M  = fmaxf(ml0.x, ml1.x);
        float w0 = ml0.y * __builtin_amdgcn_exp2f(ml0.x - M);
        float w1 = ml1.y * __builtin_amdgcn_exp2f(ml1.x - M);
        float winv = 1.f / (w0 + w1);
        Wc0[tid] = w0 * winv; Wc1[tid] = w1 * winv;
    }
    __syncthreads();

    // acc[nt] = (att @ psi)[c = w*16+quad*4+r][px = nt*16+n], compensated
    f32x4 acc[4];
#pragma unroll
    for (int nt = 0; nt < 4; ++nt) acc[nt] = (f32x4){0.f, 0.f, 0.f, 0.f};
#pragma unroll
    for (int ks = 0; ks < 2; ++ks) {
        int arow = w * 16 + n;
        bf16x8 af = *(const bf16x8*)&Abf[arow][((ks * 4 + quad) ^ (arow & 7)) << 3];
#pragma unroll
        for (int nt = 0; nt < 4; ++nt) {
            int brow = nt * 16 + n;
            int boff = ((ks * 4 + quad) ^ (brow & 7)) << 3;
            bf16x8 bh = *(const bf16x8*)&tpB[brow][boff];
            bf16x8 bl = *(const bf16x8*)&tpLo[brow][boff];
            acc[nt] = __builtin_amdgcn_mfma_f32_16x16x32_bf16(af, bh, acc[nt], 0, 0, 0);
            acc[nt] = __builtin_amdgcn_mfma_f32_16x16x32_bf16(af, bl, acc[nt], 0, 0, 0);
        }
    }

    // epilogue: cam/pam/z in f32
    const float al = alpha[0], cb = camb[0];
    float z[4] = {0.f, 0.f, 0.f, 0.f};
#pragma unroll
    for (int nt = 0; nt < 4; ++nt) {
        int px = nt * 16 + n;
        float w0 = Wc0[px], w1 = Wc1[px];
#pragma unroll
        for (int r = 0; r < 4; ++r) {
            int c = w * 16 + quad * 4 + r;
            int phys = (((c >> 3) ^ (px & 7)) << 3) | (c & 7);
            float ps  = b2f(tpB[px][phys]) + b2f(tpLo[px][phys]);
            float cam = cb * acc[nt][r] + ps;
            float oa = w0 * b2f(Opart[(((size_t)0 * 8 + b) * FI + c) * HW + p0 + px])
                     + w1 * b2f(Opart[(((size_t)1 * 8 + b) * FI + c) * HW + p0 + px]);
            float pam = al * oa + ps;
            z[nt] += Pw[c] * (cam * pam);
        }
    }
#pragma unroll
    for (int nt = 0; nt < 4; ++nt) {
        z[nt] += __shfl_xor(z[nt], 16);
        z[nt] += __shfl_xor(z[nt], 32);
    }
    if (quad == 0) {
#pragma unroll
        for (int nt = 0; nt < 4; ++nt) Zp[w][nt * 16 + n] = z[nt];
    }
    __syncthreads();
    if (tid < 64) {
        float zt = Zp[0][tid] + Zp[1][tid] + Zp[2][tid] + Zp[3][tid] + psib[0];
        float inv = pg[0] * rsqrtf(pv[0] + EPS);
        float gate = (zt - pm[0]) * inv + pbeta[0];
        daL[tid] = 1.f / (1.f + __expf(-gate));
    }
    __syncthreads();

    const int tx = lane;
    const float da = daL[tx];
#pragma unroll 8
    for (int r = 0; r < 64; ++r) {
        int cl = w + 4 * r;
        size_t idx = ((size_t)b * CIN + cl) * HW + p0 + tx;
        out[idx] = x[idx] * da;
    }
}

// ---------------------------------------------------------------------------
extern "C" void kernel_launch(void* const* d_in, const int* in_sizes, int n_in,
                              void* d_out, int out_size, void* d_ws, size_t ws_size,
                              hipStream_t stream)
{
    const float* g     = (const float*)d_in[0];
    const float* x     = (const float*)d_in[1];
    const float* Wg_w  = (const float*)d_in[2];
    const float* Wg_b  = (const float*)d_in[3];
    const float* bng_g = (const float*)d_in[4];
    const float* bng_b = (const float*)d_in[5];
    const float* bng_m = (const float*)d_in[6];
    const float* bng_v = (const float*)d_in[7];
    const float* Wx_w  = (const float*)d_in[8];
    const float* Wx_b  = (const float*)d_in[9];
    const float* bnx_g = (const float*)d_in[10];
    const float* bnx_b = (const float*)d_in[11];
    const float* bnx_m = (const float*)d_in[12];
    const float* bnx_v = (const float*)d_in[13];
    const float* psi_w = (const float*)d_in[14];
    const float* psi_b = (const float*)d_in[15];
    const float* bnp_g = (const float*)d_in[16];
    const float* bnp_b = (const float*)d_in[17];
    const float* bnp_m = (const float*)d_in[18];
    const float* bnp_v = (const float*)d_in[19];
    const float* pb_w  = (const float*)d_in[20];
    const float* pb_b  = (const float*)d_in[21];
    const float* pc_w  = (const float*)d_in[22];
    const float* pc_b  = (const float*)d_in[23];
    const float* pd_w  = (const float*)d_in[24];
    const float* pd_b  = (const float*)d_in[25];
    const float* alpha = (const float*)d_in[26];
    const float* camb  = (const float*)d_in[27];
    float* out = (float*)d_out;

    float* ws   = (float*)d_ws;
    // float-unit offsets. Opart overlays Gp (Gp dead after k_camsm).
    u16*  psiB  = (u16*)(ws);                 // fl [0,       1048576)
    u16*  psiLo = (u16*)(ws + 1048576);       // fl [1048576, 2097152)
    u16*  fbcT  = (u16*)(ws + 2097152);       // fl [2097152, 2359296)
    u16*  fdB   = (u16*)(ws + 2359296);       // fl [2359296, 3407872)
    float* att  = ws + 3407872;               // fl [3407872, 3440640)
    u16*  Wp    = (u16*)(ws + 3440640);       // fl [3440640, 3457024)
    float* Cp   = ws + 3457024;               // fl [3457024, 3457088)
    u16*  Wcat  = (u16*)(ws + 3457088);       // fl [3457088, 3459648)
    float* bcat = ws + 3459648;               // fl [3459648, 3459728)
    float* mlws = ws + 3459744;               // fl [3459744, 3590816)
    float* Gp   = ws + 3590816;               // fl [3590816, 4639392)
    u16*  Opart = (u16*)(ws + 3590816);       // fl [3590816, 5687968) overlay
                                              // total ~22.8 MB

    k_prep<<<dim3(16), 256, 0, stream>>>(Wg_w, Wg_b, bng_g, bng_b, bng_m, bng_v,
                                         Wx_w, Wx_b, bnx_g, bnx_b, bnx_m, bnx_v,
                                         pb_w, pb_b, pc_w, pc_b, pd_w, pd_b,
                                         Wp, Cp, Wcat, bcat);
    k_psi<<<dim3(64, 8), 256, 0, stream>>>(g, x, Wp, Cp, Wcat, bcat,
                                           psiB, psiLo, fbcT, fdB);
    k_gram<<<dim3(32, 8, 2), 256, 0, stream>>>(psiB, psiLo, Gp);
    k_camsm<<<dim3(8, 64), 256, 0, stream>>>(Gp, att);
    k_pam<<<dim3(8, 64, 2), 256, 0, stream>>>(fbcT, fdB, Opart, mlws);
    k_final<<<dim3(64, 8), 256, 0, stream>>>(psiB, psiLo, att, Opart, mlws, x,
                                             psi_w, psi_b, bnp_g, bnp_b, bnp_m, bnp_v,
                                             alpha, camb, out);
}

// Round 8
// 244.682 us; speedup vs baseline: 1.4943x; 1.0009x over previous
//
#include <hip/hip_runtime.h>
#include <hip/hip_bf16.h>
#include <math.h>

// Problem constants
#define BB 8
#define CIN 256
#define FI 64
#define HW 4096
#define C8 8
#define EPS 1e-5f
#define LOG2E 1.4426950408889634f

typedef __attribute__((ext_vector_type(8))) short bf16x8;
typedef __attribute__((ext_vector_type(4))) float f32x4;
typedef __attribute__((ext_vector_type(4))) unsigned u32x4;
typedef unsigned short u16;

static __device__ __forceinline__ u16 f2b(float x) {
    unsigned u = __builtin_bit_cast(unsigned, x);
    return (u16)((u + 0x8000u) >> 16);
}
static __device__ __forceinline__ unsigned pk2(float a, float b) {
    unsigned ua = __builtin_bit_cast(unsigned, a);
    unsigned ub = __builtin_bit_cast(unsigned, b);
    return ((ua + 0x8000u) >> 16) | ((ub + 0x8000u) & 0xffff0000u);
}
// single-instruction packed f32->bf16 (RNE)
static __device__ __forceinline__ unsigned cvtpk(float a, float b) {
    unsigned r;
    asm("v_cvt_pk_bf16_f32 %0, %1, %2" : "=v"(r) : "v"(a), "v"(b));
    return r;
}
static __device__ __forceinline__ float b2f(u16 v) {
    return __builtin_bit_cast(float, ((unsigned)v) << 16);
}

// ---------------------------------------------------------------------------
// K0: fold BN into psi-conv weights (Wp bf16 [64][512], Cp fp32[64]) and
// build concatenated PAM weights (Wcat bf16 [80][64], bcat fp32[80]).
// pb rows (fb = PAM query) are pre-scaled by log2(e) so the PAM softmax can
// run in exp2 domain with bare v_exp_f32.
// ---------------------------------------------------------------------------
__global__ __launch_bounds__(256) void k_prep(
    const float* __restrict__ Wg, const float* __restrict__ Wgb,
    const float* __restrict__ gg, const float* __restrict__ gbeta,
    const float* __restrict__ gm, const float* __restrict__ gv,
    const float* __restrict__ Wx, const float* __restrict__ Wxb,
    const float* __restrict__ xg, const float* __restrict__ xbeta,
    const float* __restrict__ xm, const float* __restrict__ xv,
    const float* __restrict__ pbw, const float* __restrict__ pbb,
    const float* __restrict__ pcw, const float* __restrict__ pcb,
    const float* __restrict__ pdw, const float* __restrict__ pdb,
    u16* __restrict__ Wp, float* __restrict__ Cp,
    u16* __restrict__ Wcat, float* __restrict__ bcat)
{
    const int gid = blockIdx.x * 256 + threadIdx.x;
    for (int idx = gid; idx < FI * 512; idx += 4096) {
        int o = idx >> 9, k = idx & 511;
        float s, w;
        if (k < 256) { s = gg[o] * rsqrtf(gv[o] + EPS); w = Wg[o * 256 + k]; }
        else         { s = xg[o] * rsqrtf(xv[o] + EPS); w = Wx[o * 256 + k - 256]; }
        Wp[idx] = f2b(w * s);
    }
    for (int idx = gid; idx < 80 * 64; idx += 4096) {
        int row = idx >> 6, col = idx & 63;
        float w;
        if (row < 8)       w = pbw[row * 64 + col] * LOG2E;   // exp2-domain queries
        else if (row < 16) w = pcw[(row - 8) * 64 + col];
        else               w = pdw[(row - 16) * 64 + col];
        Wcat[idx] = f2b(w);
    }
    if (blockIdx.x == 0) {
        int tid = threadIdx.x;
        if (tid < FI) {
            float ig = gg[tid] * rsqrtf(gv[tid] + EPS);
            float ix = xg[tid] * rsqrtf(xv[tid] + EPS);
            Cp[tid] = (Wgb[tid] - gm[tid]) * ig + gbeta[tid]
                    + (Wxb[tid] - xm[tid]) * ix + xbeta[tid];
        }
        if (tid >= 64 && tid < 144) {
            int r = tid - 64;
            float bv = (r < 8) ? pbb[r] * LOG2E : (r < 16 ? pcb[r - 8] : pdb[r - 16]);
            bcat[r] = bv;
        }
    }
}

// ---------------------------------------------------------------------------
// K1: psi = relu(W' @ cat(g,x) + C) via bf16 MFMA, FUSED with fbcd.
// NEW: B-fragments load DIRECTLY from global (coalesced px-direction dword
// loads, pk2-converted in regs) — removes the entire In-LDS transpose and
// 16 barriers. LDS holds only psi^T / Tfd / Tbc (3 barriers total).
// emits psiB/psiLo bf16 [B][64][4096], fbcT bf16 [B][4096][16],
// fdB bf16 [B][64][4096].
// grid (64 px-tiles, 8 b) x 256
// ---------------------------------------------------------------------------
__global__ __launch_bounds__(256) void k_psi(
    const float* __restrict__ g, const float* __restrict__ x,
    const u16* __restrict__ Wp, const float* __restrict__ Cp,
    const u16* __restrict__ Wcat, const float* __restrict__ bcat,
    u16* __restrict__ psiB, u16* __restrict__ psiLo,
    u16* __restrict__ fbcT, u16* __restrict__ fdB)
{
    const int tid  = threadIdx.x;
    const int lane = tid & 63;
    const int w    = tid >> 6;
    const int n    = lane & 15;
    const int quad = lane >> 4;
    const int b    = blockIdx.y;
    const int p0   = blockIdx.x * 64;

    __shared__ u16 InT[64][72];   // psi^T [px][c]; later Tfd [ch][px]
    __shared__ u16 Tbc[64][16];   // [px][out16]

    f32x4 acc[4];
#pragma unroll
    for (int mt = 0; mt < 4; ++mt) acc[mt] = (f32x4){0.f, 0.f, 0.f, 0.f};

    // conv: B-frag direct from global. lane covers px = p0 + w*16 + n,
    // ch = kglob + quad*8 + j (stride-HW dword loads, coalesced across n).
    const size_t pxoff = (size_t)p0 + w * 16 + n;
#pragma unroll
    for (int kc = 0; kc < 8; ++kc) {
        const float* src = (kc < 4) ? g : x;
        const int ch0 = (kc & 3) * 64;
        const float* base = src + ((size_t)b * CIN + ch0 + quad * 8) * HW + pxoff;
#pragma unroll
        for (int ks = 0; ks < 2; ++ks) {
            const float* bp = base + (size_t)(ks * 32) * HW;
            float f0 = bp[0 * HW], f1 = bp[1 * HW], f2 = bp[2 * HW], f3 = bp[3 * HW];
            float f4 = bp[4 * HW], f5 = bp[5 * HW], f6 = bp[6 * HW], f7 = bp[7 * HW];
            u32x4 t = {pk2(f0, f1), pk2(f2, f3), pk2(f4, f5), pk2(f6, f7)};
            bf16x8 bfrag = __builtin_bit_cast(bf16x8, t);
            const int kglob = kc * 64 + ks * 32;
#pragma unroll
            for (int mt = 0; mt < 4; ++mt) {
                bf16x8 af = *(const bf16x8*)&Wp[(mt * 16 + n) * 512 + kglob + quad * 8];
                acc[mt] = __builtin_amdgcn_mfma_f32_16x16x32_bf16(
                              af, bfrag, acc[mt], 0, 0, 0);
            }
        }
    }

    // bias + relu; store psiB(hi)+psiLo; build psi^T in InT
    float pv[4][4];
#pragma unroll
    for (int mt = 0; mt < 4; ++mt)
#pragma unroll
        for (int r = 0; r < 4; ++r) {
            int c = mt * 16 + quad * 4 + r;
            float v = acc[mt][r] + Cp[c];
            v = v > 0.f ? v : 0.f;
            pv[mt][r] = v;
            u16 hb = f2b(v);
            size_t idx = ((size_t)b * FI + c) * HW + p0 + w * 16 + n;
            psiB[idx]  = hb;
            psiLo[idx] = f2b(v - b2f(hb));
        }
#pragma unroll
    for (int mt = 0; mt < 4; ++mt) {
        *(unsigned*)&InT[w * 16 + n][mt * 16 + quad * 4]     = cvtpk(pv[mt][0], pv[mt][1]);
        *(unsigned*)&InT[w * 16 + n][mt * 16 + quad * 4 + 2] = cvtpk(pv[mt][2], pv[mt][3]);
    }
    __syncthreads();

    // fbcd MFMAs: A = psi^T rows (px), B = Wcat (L2-resident)
    f32x4 facc[5];
#pragma unroll
    for (int nt = 0; nt < 5; ++nt) facc[nt] = (f32x4){0.f, 0.f, 0.f, 0.f};
#pragma unroll
    for (int ks = 0; ks < 2; ++ks) {
        bf16x8 af = *(const bf16x8*)&InT[w * 16 + n][ks * 32 + quad * 8];
#pragma unroll
        for (int nt = 0; nt < 5; ++nt) {
            bf16x8 bf = *(const bf16x8*)&Wcat[(nt * 16 + n) * FI + ks * 32 + quad * 8];
            facc[nt] = __builtin_amdgcn_mfma_f32_16x16x32_bf16(af, bf, facc[nt], 0, 0, 0);
        }
    }
    __syncthreads();   // all psi^T reads done; reuse InT as Tfd [ch][px]

    {
        float bias = bcat[n];
#pragma unroll
        for (int r = 0; r < 4; ++r)
            Tbc[w * 16 + quad * 4 + r][n] = f2b(facc[0][r] + bias);
    }
#pragma unroll
    for (int nt = 1; nt < 5; ++nt) {
        int ch = (nt - 1) * 16 + n;
        float bias = bcat[nt * 16 + n];
        *(unsigned*)&InT[ch][w * 16 + quad * 4]     = cvtpk(facc[nt][0] + bias, facc[nt][1] + bias);
        *(unsigned*)&InT[ch][w * 16 + quad * 4 + 2] = cvtpk(facc[nt][2] + bias, facc[nt][3] + bias);
    }
    __syncthreads();
    {   // fbcT: 64 rows x 16 el
        int row = tid >> 2, part = tid & 3;
        uint2 v = *(const uint2*)&Tbc[row][part * 4];
        *(uint2*)&fbcT[((size_t)b * HW + p0 + row) * 16 + part * 4] = v;
    }
#pragma unroll
    for (int rep = 0; rep < 2; ++rep) {   // fdB: 64 ch x 64 px
        int t = rep * 256 + tid;
        int ch = t >> 3, seg = t & 7;
        bf16x8 v = *(const bf16x8*)&InT[ch][seg * 8];
        *(bf16x8*)&fdB[((size_t)b * FI + ch) * HW + p0 + seg * 8] = v;
    }
}

// ---------------------------------------------------------------------------
// K3a: Gram partials via compensated bf16 MFMA (hi*hi + hi*lo + lo*hi).
// grid (32 slices, 8 b, 2 nt-half) x 256 -> Gp[s][b][64][64]
// ---------------------------------------------------------------------------
__global__ __launch_bounds__(256) void k_gram(
    const u16* __restrict__ psiB, const u16* __restrict__ psiLo,
    float* __restrict__ Gp)
{
    const int tid  = threadIdx.x;
    const int lane = tid & 63;
    const int w    = tid >> 6;
    const int n    = lane & 15;
    const int quad = lane >> 4;
    const int s    = blockIdx.x;
    const int b    = blockIdx.y;
    const int zz   = blockIdx.z;   // nt-half: cols zz*32 .. zz*32+31

    f32x4 acc[2];
#pragma unroll
    for (int nt = 0; nt < 2; ++nt) acc[nt] = (f32x4){0.f, 0.f, 0.f, 0.f};

    for (int ks = 0; ks < 4; ++ks) {
        const int k0 = s * 128 + ks * 32;
        const size_t ra = ((size_t)b * FI + w * 16 + n) * HW + k0 + quad * 8;
        bf16x8 ah = *(const bf16x8*)&psiB[ra];
        bf16x8 al = *(const bf16x8*)&psiLo[ra];
#pragma unroll
        for (int nt = 0; nt < 2; ++nt) {
            const size_t rb = ((size_t)b * FI + zz * 32 + nt * 16 + n) * HW + k0 + quad * 8;
            bf16x8 bh = *(const bf16x8*)&psiB[rb];
            bf16x8 bl = *(const bf16x8*)&psiLo[rb];
            acc[nt] = __builtin_amdgcn_mfma_f32_16x16x32_bf16(ah, bh, acc[nt], 0, 0, 0);
            acc[nt] = __builtin_amdgcn_mfma_f32_16x16x32_bf16(ah, bl, acc[nt], 0, 0, 0);
            acc[nt] = __builtin_amdgcn_mfma_f32_16x16x32_bf16(al, bh, acc[nt], 0, 0, 0);
        }
    }
#pragma unroll
    for (int nt = 0; nt < 2; ++nt)
#pragma unroll
        for (int r = 0; r < 4; ++r) {
            int i = w * 16 + quad * 4 + r;
            Gp[(((size_t)s * 8 + b) * 64 + i) * 64 + zz * 32 + nt * 16 + n] = acc[nt][r];
        }
}

// ---------------------------------------------------------------------------
// K3b: CAM softmax of (rowmax - G).  grid (8 b, 64 row) x 256.
// ---------------------------------------------------------------------------
__global__ __launch_bounds__(256) void k_camsm(
    const float* __restrict__ Gp, float* __restrict__ att)
{
    const int tid = threadIdx.x, tx = tid & 63, ty = tid >> 6;
    const int b = blockIdx.x, i = blockIdx.y;
    __shared__ float part[4][64];

    float gs = 0.f;
#pragma unroll
    for (int j = 0; j < 8; ++j) {
        int s = ty * 8 + j;
        gs += Gp[(((size_t)s * 8 + b) * 64 + i) * 64 + tx];
    }
    part[ty][tx] = gs;
    __syncthreads();
    if (tid < 64) {
        float gsum = part[0][tx] + part[1][tx] + part[2][tx] + part[3][tx];
        float M = gsum;
#pragma unroll
        for (int msk = 1; msk < 64; msk <<= 1) M = fmaxf(M, __shfl_xor(M, msk));
        float a = M - gsum;
        float m2 = a;
#pragma unroll
        for (int msk = 1; msk < 64; msk <<= 1) m2 = fmaxf(m2, __shfl_xor(m2, msk));
        float p = __expf(a - m2);
        float ssum = p;
#pragma unroll
        for (int msk = 1; msk < 64; msk <<= 1) ssum += __shfl_xor(ssum, msk);
        att[((size_t)b * 64 + i) * 64 + tx] = p / ssum;
    }
}

// ---------------------------------------------------------------------------
// K5: PAM flash attention. (unchanged from R7 — control)
// ---------------------------------------------------------------------------
__global__ __launch_bounds__(256) void k_pam(
    const u16* __restrict__ fbcT, const u16* __restrict__ fdB,
    u16* __restrict__ Opart, float* __restrict__ ml)
{
    const int tid  = threadIdx.x;
    const int lane = tid & 63;
    const int w    = tid >> 6;
    const int n    = lane & 15;
    const int quad = lane >> 4;
    const int b    = blockIdx.x;
    const int i0   = blockIdx.y * 64;
    const int p    = blockIdx.z;
    const int jstart = p * 32, jend = jstart + 32;

    __shared__ u16 Ks[2][68][8];    // [buf][key][k0..7]; rows 64..67 zero pad
    __shared__ u16 Vs[2][64][64];   // [buf][chan][key], 128B rows, swizzled slots
    __shared__ u16 Ps[4][16][64];   // per-wave P^T [q_local][key], swizzled slots

    if (tid < 16) {
        ((unsigned*)&Ks[0][64][0])[tid] = 0u;
        ((unsigned*)&Ks[1][64][0])[tid] = 0u;
    }

    bf16x8 qfrag = {};
    if (quad == 0)
        qfrag = *(const bf16x8*)&fbcT[((size_t)b * HW + i0 + w * 16 + n) * 16];

    const int kkey = tid >> 1, khalf = tid & 1;
    const int vch  = tid >> 3, vseg  = tid & 7;
    const int vslot = (vseg ^ (vch & 7)) << 3;
    const int pswz  = n & 7;

    const u16* kp = fbcT + ((size_t)b * HW + jstart * 64) * 16 + 8;
    const u16* vp = fdB + (size_t)b * FI * HW + jstart * 64;

    uint2 kr0 = make_uint2(0u, 0u), kr1 = make_uint2(0u, 0u);
    bf16x8 v0a, v0b, v1a, v1b;
    if (tid < 128) {
        kr0 = *(const uint2*)(kp + (size_t)kkey * 16 + khalf * 4);
        kr1 = *(const uint2*)(kp + 1024 + (size_t)kkey * 16 + khalf * 4);
    }
    v0a = *(const bf16x8*)(vp + (size_t)vch * HW + vseg * 8);
    v0b = *(const bf16x8*)(vp + (size_t)(32 + vch) * HW + vseg * 8);
    v1a = *(const bf16x8*)(vp + 64 + (size_t)vch * HW + vseg * 8);
    v1b = *(const bf16x8*)(vp + 64 + (size_t)(32 + vch) * HW + vseg * 8);

    f32x4 oacc[4];
#pragma unroll
    for (int mt = 0; mt < 4; ++mt) oacc[mt] = (f32x4){0.f, 0.f, 0.f, 0.f};
    float m = -1e30f, l = 0.f;

#define PAM_STEP(BUF)                                                           \
    {                                                                           \
        f32x4 s[4];                                                             \
        __builtin_amdgcn_s_setprio(1);                                          \
        _Pragma("unroll")                                                       \
        for (int mt = 0; mt < 4; ++mt) {                                        \
            bf16x8 af = *(const bf16x8*)&Ks[BUF][mt * 16 + n + quad][0];        \
            s[mt] = __builtin_amdgcn_mfma_f32_16x16x32_bf16(                    \
                        af, qfrag, (f32x4){0.f, 0.f, 0.f, 0.f}, 0, 0, 0);       \
        }                                                                       \
        __builtin_amdgcn_s_setprio(0);                                          \
        float cm = fmaxf(fmaxf(s[0][0], s[0][1]), s[0][2]);                     \
        cm = fmaxf(fmaxf(cm, s[0][3]), s[1][0]);                                \
        cm = fmaxf(fmaxf(cm, s[1][1]), s[1][2]);                                \
        cm = fmaxf(fmaxf(cm, s[1][3]), s[2][0]);                                \
        cm = fmaxf(fmaxf(cm, s[2][1]), s[2][2]);                                \
        cm = fmaxf(fmaxf(cm, s[2][3]), s[3][0]);                                \
        cm = fmaxf(fmaxf(cm, s[3][1]), s[3][2]);                                \
        cm = fmaxf(cm, s[3][3]);                                                \
        cm = fmaxf(cm, __shfl_xor(cm, 16));                                     \
        cm = fmaxf(cm, __shfl_xor(cm, 32));                                     \
        if (__any(cm > m + 8.f)) {                                              \
            float mnew  = fmaxf(m, cm);                                         \
            float scale = __builtin_amdgcn_exp2f(m - mnew);                     \
            l *= scale;                                                         \
            _Pragma("unroll")                                                   \
            for (int mt = 0; mt < 4; ++mt) {                                    \
                oacc[mt][0] *= scale; oacc[mt][1] *= scale;                     \
                oacc[mt][2] *= scale; oacc[mt][3] *= scale;                     \
            }                                                                   \
            m = mnew;                                                           \
        }                                                                       \
        float psum = 0.f;                                                       \
        unsigned pw[4][2];                                                      \
        _Pragma("unroll")                                                       \
        for (int mt = 0; mt < 4; ++mt) {                                        \
            float e0 = __builtin_amdgcn_exp2f(s[mt][0] - m);                    \
            float e1 = __builtin_amdgcn_exp2f(s[mt][1] - m);                    \
            float e2 = __builtin_amdgcn_exp2f(s[mt][2] - m);                    \
            float e3 = __builtin_amdgcn_exp2f(s[mt][3] - m);                    \
            psum += (e0 + e1) + (e2 + e3);                                      \
            pw[mt][0] = cvtpk(e0, e1);                                          \
            pw[mt][1] = cvtpk(e2, e3);                                          \
        }                                                                       \
        l += psum;                                                              \
        _Pragma("unroll")                                                       \
        for (int mt = 0; mt < 4; ++mt) {                                        \
            int so = (((mt * 2 + (quad >> 1)) ^ pswz) << 3) + ((quad & 1) << 2);\
            *(uint2*)&Ps[w][n][so] = make_uint2(pw[mt][0], pw[mt][1]);          \
        }                                                                       \
        __builtin_amdgcn_s_setprio(1);                                          \
        _Pragma("unroll")                                                       \
        for (int k0 = 0; k0 < 2; ++k0) {                                        \
            bf16x8 pf = *(const bf16x8*)&Ps[w][n][((k0 * 4 + quad) ^ pswz) << 3];\
            _Pragma("unroll")                                                   \
            for (int mt = 0; mt < 4; ++mt) {                                    \
                bf16x8 vf = *(const bf16x8*)                                    \
                    &Vs[BUF][mt * 16 + n][((k0 * 4 + quad) ^ pswz) << 3];       \
                oacc[mt] = __builtin_amdgcn_mfma_f32_16x16x32_bf16(             \
                               vf, pf, oacc[mt], 0, 0, 0);                      \
            }                                                                   \
        }                                                                       \
        __builtin_amdgcn_s_setprio(0);                                          \
    }

    for (int jc = jstart; jc < jend; jc += 2) {
        if (tid < 128) *(uint2*)&Ks[0][kkey][khalf * 4] = kr0;
        *(bf16x8*)&Vs[0][vch][vslot]      = v0a;
        *(bf16x8*)&Vs[0][32 + vch][vslot] = v0b;
        if (jc + 2 < jend) {
            if (tid < 128)
                kr0 = *(const uint2*)(kp + 2048 + (size_t)kkey * 16 + khalf * 4);
            v0a = *(const bf16x8*)(vp + 128 + (size_t)vch * HW + vseg * 8);
            v0b = *(const bf16x8*)(vp + 128 + (size_t)(32 + vch) * HW + vseg * 8);
        }
        __syncthreads();
        PAM_STEP(0)

        if (tid < 128) *(uint2*)&Ks[1][kkey][khalf * 4] = kr1;
        *(bf16x8*)&Vs[1][vch][vslot]      = v1a;
        *(bf16x8*)&Vs[1][32 + vch][vslot] = v1b;
        if (jc + 3 < jend) {
            if (tid < 128)
                kr1 = *(const uint2*)(kp + 3072 + (size_t)kkey * 16 + khalf * 4);
            v1a = *(const bf16x8*)(vp + 192 + (size_t)vch * HW + vseg * 8);
            v1b = *(const bf16x8*)(vp + 192 + (size_t)(32 + vch) * HW + vseg * 8);
        }
        kp += 2048;
        vp += 128;
        __syncthreads();
        PAM_STEP(1)
    }
#undef PAM_STEP

    l += __shfl_xor(l, 16);
    l += __shfl_xor(l, 32);
    const float rl = 1.f / l;
#pragma unroll
    for (int mt = 0; mt < 4; ++mt)
#pragma unroll
        for (int r = 0; r < 4; ++r) {
            int c = mt * 16 + quad * 4 + r;
            Opart[(((size_t)p * 8 + b) * FI + c) * HW + i0 + w * 16 + n] =
                f2b(oacc[mt][r] * rl);
        }
    if (quad == 0)
        ((float2*)ml)[((size_t)p * 8 + b) * HW + i0 + w * 16 + n] = make_float2(m, l);
}

// ---------------------------------------------------------------------------
// K4: combine PAM partials + cam apply + psi-conv + BN + sigmoid + x * da.
// (unchanged from R6)
// ---------------------------------------------------------------------------
__global__ __launch_bounds__(256) void k_final(
    const u16* __restrict__ psiB, const u16* __restrict__ psiLo,
    const float* __restrict__ att,
    const u16* __restrict__ Opart, const float* __restrict__ ml,
    const float* __restrict__ x,
    const float* __restrict__ psiw, const float* __restrict__ psib,
    const float* __restrict__ pg, const float* __restrict__ pbeta,
    const float* __restrict__ pm, const float* __restrict__ pv,
    const float* __restrict__ alpha, const float* __restrict__ camb,
    float* __restrict__ out)
{
    const int tid  = threadIdx.x;
    const int lane = tid & 63;
    const int w    = tid >> 6;
    const int n    = lane & 15;
    const int quad = lane >> 4;
    const int b = blockIdx.y, p0 = blockIdx.x * 64;

    __shared__ u16 Abf[64][64];    // att bf16, rows=c, swizzled 16B slots
    __shared__ u16 tpB[64][64];    // psi hi, rows=px cols=c, swizzled
    __shared__ u16 tpLo[64][64];   // psi lo
    __shared__ float Wc0[64], Wc1[64], Pw[64], daL[64];
    __shared__ float Zp[4][64];

    // stage A = att (rows c, bf16, swizzled)
    {
        int c = tid >> 2, seg = tid & 3;
        const float* ap = &att[((size_t)b * 64 + c) * 64 + seg * 16];
        float4 v0 = *(const float4*)(ap);
        float4 v1 = *(const float4*)(ap + 4);
        float4 v2 = *(const float4*)(ap + 8);
        float4 v3 = *(const float4*)(ap + 12);
        float vv[16] = {v0.x, v0.y, v0.z, v0.w, v1.x, v1.y, v1.z, v1.w,
                        v2.x, v2.y, v2.z, v2.w, v3.x, v3.y, v3.z, v3.w};
#pragma unroll
        for (int j = 0; j < 8; ++j) {
            int d0 = seg * 16 + j * 2;
            int phys = (((d0 >> 3) ^ (c & 7)) << 3) | (d0 & 7);
            *(unsigned*)&Abf[c][phys] = cvtpk(vv[2 * j], vv[2 * j + 1]);
        }
    }
    // stage tp = psi^T (rows px, cols c; hi/lo; swizzled)
    {
        int px = tid & 63, grp = tid >> 6;
#pragma unroll
        for (int cc = 0; cc < 16; cc += 2) {
            int c = grp * 16 + cc;
            size_t i0 = ((size_t)b * FI + c) * HW + p0 + px;
            unsigned hb = ((unsigned)psiB[i0]) | (((unsigned)psiB[i0 + HW]) << 16);
            unsigned lb = ((unsigned)psiLo[i0]) | (((unsigned)psiLo[i0 + HW]) << 16);
            int phys = (((c >> 3) ^ (px & 7)) << 3) | (c & 7);
            *(unsigned*)&tpB[px][phys]  = hb;
            *(unsigned*)&tpLo[px][phys] = lb;
        }
    }
    if (tid < 64) {
        Pw[tid] = psiw[tid];
        float2 ml0 = ((const float2*)ml)[((size_t)0 * 8 + b) * HW + p0 + tid];
        float2 ml1 = ((const float2*)ml)[((size_t)1 * 8 + b) * HW + p0 + tid];
        float M  = fmaxf(ml0.x, ml1.x);
        float w0 = ml0.y * __builtin_amdgcn_exp2f(ml0.x - M);
        float w1 = ml1.y * __builtin_amdgcn_exp2f(ml1.x - M);
        float winv = 1.f / (w0 + w1);
        Wc0[tid] = w0 * winv; Wc1[tid] = w1 * winv;
    }
    __syncthreads();

    // acc[nt] = (att @ psi)[c = w*16+quad*4+r][px = nt*16+n], compensated
    f32x4 acc[4];
#pragma unroll
    for (int nt = 0; nt < 4; ++nt) acc[nt] = (f32x4){0.f, 0.f, 0.f, 0.f};
#pragma unroll
    for (int ks = 0; ks < 2; ++ks) {
        int arow = w * 16 + n;
        bf16x8 af = *(const bf16x8*)&Abf[arow][((ks * 4 + quad) ^ (arow & 7)) << 3];
#pragma unroll
        for (int nt = 0; nt < 4; ++nt) {
            int brow = nt * 16 + n;
            int boff = ((ks * 4 + quad) ^ (brow & 7)) << 3;
            bf16x8 bh = *(const bf16x8*)&tpB[brow][boff];
            bf16x8 bl = *(const bf16x8*)&tpLo[brow][boff];
            acc[nt] = __builtin_amdgcn_mfma_f32_16x16x32_bf16(af, bh, acc[nt], 0, 0, 0);
            acc[nt] = __builtin_amdgcn_mfma_f32_16x16x32_bf16(af, bl, acc[nt], 0, 0, 0);
        }
    }

    // epilogue: cam/pam/z in f32
    const float al = alpha[0], cb = camb[0];
    float z[4] = {0.f, 0.f, 0.f, 0.f};
#pragma unroll
    for (int nt = 0; nt < 4; ++nt) {
        int px = nt * 16 + n;
        float w0 = Wc0[px], w1 = Wc1[px];
#pragma unroll
        for (int r = 0; r < 4; ++r) {
            int c = w * 16 + quad * 4 + r;
            int phys = (((c >> 3) ^ (px & 7)) << 3) | (c & 7);
            float ps  = b2f(tpB[px][phys]) + b2f(tpLo[px][phys]);
            float cam = cb * acc[nt][r] + ps;
            float oa = w0 * b2f(Opart[(((size_t)0 * 8 + b) * FI + c) * HW + p0 + px])
                     + w1 * b2f(Opart[(((size_t)1 * 8 + b) * FI + c) * HW + p0 + px]);
            float pam = al * oa + ps;
            z[nt] += Pw[c] * (cam * pam);
        }
    }
#pragma unroll
    for (int nt = 0; nt < 4; ++nt) {
        z[nt] += __shfl_xor(z[nt], 16);
        z[nt] += __shfl_xor(z[nt], 32);
    }
    if (quad == 0) {
#pragma unroll
        for (int nt = 0; nt < 4; ++nt) Zp[w][nt * 16 + n] = z[nt];
    }
    __syncthreads();
    if (tid < 64) {
        float zt = Zp[0][tid] + Zp[1][tid] + Zp[2][tid] + Zp[3][tid] + psib[0];
        float inv = pg[0] * rsqrtf(pv[0] + EPS);
        float gate = (zt - pm[0]) * inv + pbeta[0];
        daL[tid] = 1.f / (1.f + __expf(-gate));
    }
    __syncthreads();

    const int tx = lane;
    const float da = daL[tx];
#pragma unroll 8
    for (int r = 0; r < 64; ++r) {
        int cl = w + 4 * r;
        size_t idx = ((size_t)b * CIN + cl) * HW + p0 + tx;
        out[idx] = x[idx] * da;
    }
}

// ---------------------------------------------------------------------------
extern "C" void kernel_launch(void* const* d_in, const int* in_sizes, int n_in,
                              void* d_out, int out_size, void* d_ws, size_t ws_size,
                              hipStream_t stream)
{
    const float* g     = (const float*)d_in[0];
    const float* x     = (const float*)d_in[1];
    const float* Wg_w  = (const float*)d_in[2];
    const float* Wg_b  = (const float*)d_in[3];
    const float* bng_g = (const float*)d_in[4];
    const float* bng_b = (const float*)d_in[5];
    const float* bng_m = (const float*)d_in[6];
    const float* bng_v = (const float*)d_in[7];
    const float* Wx_w  = (const float*)d_in[8];
    const float* Wx_b  = (const float*)d_in[9];
    const float* bnx_g = (const float*)d_in[10];
    const float* bnx_b = (const float*)d_in[11];
    const float* bnx_m = (const float*)d_in[12];
    const float* bnx_v = (const float*)d_in[13];
    const float* psi_w = (const float*)d_in[14];
    const float* psi_b = (const float*)d_in[15];
    const float* bnp_g = (const float*)d_in[16];
    const float* bnp_b = (const float*)d_in[17];
    const float* bnp_m = (const float*)d_in[18];
    const float* bnp_v = (const float*)d_in[19];
    const float* pb_w  = (const float*)d_in[20];
    const float* pb_b  = (const float*)d_in[21];
    const float* pc_w  = (const float*)d_in[22];
    const float* pc_b  = (const float*)d_in[23];
    const float* pd_w  = (const float*)d_in[24];
    const float* pd_b  = (const float*)d_in[25];
    const float* alpha = (const float*)d_in[26];
    const float* camb  = (const float*)d_in[27];
    float* out = (float*)d_out;

    float* ws   = (float*)d_ws;
    // float-unit offsets. Opart overlays Gp (Gp dead after k_camsm).
    u16*  psiB  = (u16*)(ws);                 // fl [0,       1048576)
    u16*  psiLo = (u16*)(ws + 1048576);       // fl [1048576, 2097152)
    u16*  fbcT  = (u16*)(ws + 2097152);       // fl [2097152, 2359296)
    u16*  fdB   = (u16*)(ws + 2359296);       // fl [2359296, 3407872)
    float* att  = ws + 3407872;               // fl [3407872, 3440640)
    u16*  Wp    = (u16*)(ws + 3440640);       // fl [3440640, 3457024)
    float* Cp   = ws + 3457024;               // fl [3457024, 3457088)
    u16*  Wcat  = (u16*)(ws + 3457088);       // fl [3457088, 3459648)
    float* bcat = ws + 3459648;               // fl [3459648, 3459728)
    float* mlws = ws + 3459744;               // fl [3459744, 3590816)
    float* Gp   = ws + 3590816;               // fl [3590816, 4639392)
    u16*  Opart = (u16*)(ws + 3590816);       // fl [3590816, 5687968) overlay
                                              // total ~22.8 MB

    k_prep<<<dim3(16), 256, 0, stream>>>(Wg_w, Wg_b, bng_g, bng_b, bng_m, bng_v,
                                         Wx_w, Wx_b, bnx_g, bnx_b, bnx_m, bnx_v,
                                         pb_w, pb_b, pc_w, pc_b, pd_w, pd_b,
                                         Wp, Cp, Wcat, bcat);
    k_psi<<<dim3(64, 8), 256, 0, stream>>>(g, x, Wp, Cp, Wcat, bcat,
                                           psiB, psiLo, fbcT, fdB);
    k_gram<<<dim3(32, 8, 2), 256, 0, stream>>>(psiB, psiLo, Gp);
    k_camsm<<<dim3(8, 64), 256, 0, stream>>>(Gp, att);
    k_pam<<<dim3(8, 64, 2), 256, 0, stream>>>(fbcT, fdB, Opart, mlws);
    k_final<<<dim3(64, 8), 256, 0, stream>>>(psiB, psiLo, att, Opart, mlws, x,
                                             psi_w, psi_b, bnp_g, bnp_b, bnp_m, bnp_v,
                                             alpha, camb, out);
}